// Round 1
// baseline (3889.878 us; speedup 1.0000x reference)
//
#include <hip/hip_runtime.h>
#include <hip/hip_bf16.h>

#define N_ROWS 32768
#define K_CODES 8192
#define C_DIM 256
#define S_SZ 4096   // 16*16*16
#define DECAYF 0.95f
#define COMMITF 0.25f
#define EPSF 1e-5f

// d_out layout (floats), reference return order
#define OFF_QUANT 0
#define OFF_ELOSS 8388608
#define OFF_PERP  8388609
#define OFF_UNIQ  8388610
#define OFF_NCB   8388611
#define OFF_NCNT  10485763
#define OFF_NW    10493955
#define OFF_IDX   12591107

#define SWZ(r) ((((r) >> 2) & 7) << 2)

// ---------------- Kernel A: codebook row squared-norms ----------------
__global__ void knorm(const float* __restrict__ cb, float* __restrict__ cnorm) {
    const int wid  = threadIdx.x >> 6;
    const int lane = threadIdx.x & 63;
    const int row  = blockIdx.x * 4 + wid;
    const float4 v = *(const float4*)(cb + (size_t)row * C_DIM + lane * 4);
    float s = v.x * v.x + v.y * v.y + v.z * v.z + v.w * v.w;
    #pragma unroll
    for (int off = 32; off; off >>= 1) s += __shfl_down(s, off);
    if (lane == 0) cnorm[row] = s;
}

// ---------------- Kernel B: distance argmin (the GEMM) ----------------
// Block: 256 threads; tile 64 rows x 64-code chunks; per-thread 4x4.
__launch_bounds__(256, 1)
__global__ void kargmin(const float* __restrict__ x, const float* __restrict__ cb,
                        const float* __restrict__ cnorm, float* __restrict__ idxf) {
    __shared__ float xs[64][256];  // x tile, XOR-swizzled columns
    __shared__ float es[64][256];  // codebook chunk, XOR-swizzled columns

    const int t  = threadIdx.x;
    const int n0 = blockIdx.x * 64;
    const int b  = n0 >> 12;
    const int s0 = n0 & 4095;

    // stage full x tile (64 rows x 256 features), coalesced on the s axis
    {
        const int r  = t & 63;
        const int c0 = t >> 6;
        const float* xb = x + (size_t)b * C_DIM * S_SZ + s0 + r;
        const int sw = SWZ(r);
        #pragma unroll 8
        for (int cc = 0; cc < 64; ++cc) {
            int c = cc * 4 + c0;
            xs[r][c ^ sw] = xb[(size_t)c * S_SZ];
        }
    }

    const int mg  = t >> 4;        // 0..15 -> rows m0..m0+3
    const int ng  = t & 15;        // 0..15 -> codes nn0..nn0+3
    const int m0  = mg * 4;
    const int nn0 = ng * 4;
    const int swm = SWZ(m0);       // same for m0..m0+3
    const int swn = SWZ(nn0);      // same for nn0..nn0+3

    float minv[4] = {1e30f, 1e30f, 1e30f, 1e30f};
    int   mini[4] = {0, 0, 0, 0};

    for (int k0 = 0; k0 < K_CODES; k0 += 64) {
        __syncthreads();  // previous chunk fully consumed
        // stage 64-code chunk: one wave per code row, float4 per lane
        {
            const int lane = t & 63;
            const int cw   = t >> 6;
            #pragma unroll
            for (int p = 0; p < 16; ++p) {
                int code = p * 4 + cw;
                float4 v = *(const float4*)(cb + (size_t)(k0 + code) * C_DIM + lane * 4);
                *(float4*)&es[code][(lane * 4) ^ SWZ(code)] = v;
            }
        }
        // prefetch the chunk's codebook norms (L2-hot)
        float cn[4];
        #pragma unroll
        for (int j = 0; j < 4; ++j) cn[j] = cnorm[k0 + nn0 + j];
        __syncthreads();

        float acc[4][4];
        #pragma unroll
        for (int i = 0; i < 4; ++i)
            #pragma unroll
            for (int j = 0; j < 4; ++j) acc[i][j] = 0.f;

        #pragma unroll 4
        for (int c = 0; c < C_DIM; c += 4) {
            float4 xa[4], eb[4];
            #pragma unroll
            for (int i = 0; i < 4; ++i) xa[i] = *(const float4*)&xs[m0 + i][c ^ swm];
            #pragma unroll
            for (int j = 0; j < 4; ++j) eb[j] = *(const float4*)&es[nn0 + j][c ^ swn];
            #pragma unroll
            for (int i = 0; i < 4; ++i)
                #pragma unroll
                for (int j = 0; j < 4; ++j)
                    acc[i][j] += xa[i].x * eb[j].x + xa[i].y * eb[j].y +
                                 xa[i].z * eb[j].z + xa[i].w * eb[j].w;
        }

        #pragma unroll
        for (int j = 0; j < 4; ++j) {
            const int kg = k0 + nn0 + j;
            #pragma unroll
            for (int i = 0; i < 4; ++i) {
                float dist = fmaf(-2.f, acc[i][j], cn[j]);
                if (dist < minv[i]) { minv[i] = dist; mini[i] = kg; }  // '<' keeps first occurrence
            }
        }
    }

    // reduce across the 16 lanes sharing this m-group (first-index tie-break)
    #pragma unroll
    for (int off = 1; off < 16; off <<= 1) {
        #pragma unroll
        for (int i = 0; i < 4; ++i) {
            float ov = __shfl_xor(minv[i], off);
            int   oi = __shfl_xor(mini[i], off);
            if (ov < minv[i] || (ov == minv[i] && oi < mini[i])) { minv[i] = ov; mini[i] = oi; }
        }
    }
    if (ng == 0) {
        #pragma unroll
        for (int i = 0; i < 4; ++i) idxf[n0 + m0 + i] = (float)mini[i];
    }
}

// ---------------- Kernel C: quantize + e_loss partials + segment sums ----------------
__global__ void kquant(const float* __restrict__ x, const float* __restrict__ cb,
                       const float* __restrict__ idxf, float* __restrict__ qout,
                       float* __restrict__ dw, float* __restrict__ counts,
                       float* __restrict__ loss_arr) {
    const int t   = threadIdx.x;
    const int bid = blockIdx.x;
    const int sc  = bid & 15;
    const int c   = (bid >> 4) & 255;
    const int b   = bid >> 12;
    const int s   = sc * 256 + t;
    const int n   = b * 4096 + s;
    const int k   = (int)idxf[n];

    const size_t xoff = ((size_t)b * C_DIM + c) * S_SZ + s;
    const float xv = x[xoff];
    const float q  = cb[(size_t)k * C_DIM + c];
    qout[xoff] = xv + (q - xv);            // straight-through value, reference arithmetic
    atomicAdd(&dw[(size_t)k * C_DIM + c], xv);
    if (c == 0) atomicAdd(&counts[k], 1.0f);

    float d = q - xv;
    float p = d * d;
    #pragma unroll
    for (int off = 32; off; off >>= 1) p += __shfl_down(p, off);
    __shared__ float ps[4];
    if ((t & 63) == 0) ps[t >> 6] = p;
    __syncthreads();
    if (t == 0) atomicAdd(&loss_arr[bid & 255], ps[0] + ps[1] + ps[2] + ps[3]);
}

// ---------------- Kernel D: perplexity / unique / e_loss ----------------
__global__ void kstats(const float* __restrict__ counts, const float* __restrict__ loss_arr,
                       float* __restrict__ out) {
    const int t = threadIdx.x;
    float nz = 0.f, s = 0.f;
    for (int k = t; k < K_CODES; k += 256) {
        float cnt = counts[k];
        if (cnt != 0.f) nz += 1.f;
        float p = cnt * (1.f / 32768.f);
        s += p * logf(p + 1e-10f);
    }
    float ls = loss_arr[t];
    #pragma unroll
    for (int off = 32; off; off >>= 1) {
        s  += __shfl_down(s, off);
        nz += __shfl_down(nz, off);
        ls += __shfl_down(ls, off);
    }
    __shared__ float ss[4], zz[4], ll[4];
    const int wid = t >> 6, lane = t & 63;
    if (lane == 0) { ss[wid] = s; zz[wid] = nz; ll[wid] = ls; }
    __syncthreads();
    if (t == 0) {
        float st = ss[0] + ss[1] + ss[2] + ss[3];
        float zt = zz[0] + zz[1] + zz[2] + zz[3];
        float lt = ll[0] + ll[1] + ll[2] + ll[3];
        out[OFF_ELOSS] = COMMITF * lt / 8388608.f;
        out[OFF_PERP]  = expf(-st);
        out[OFF_UNIQ]  = zt;
    }
}

// ---------------- Kernel E: EMA finalize (in-place on the accumulators) ----------------
__global__ void kfinal(const float* __restrict__ ema_c, const float* __restrict__ ema_w,
                       float* __restrict__ counts /* raw -> new_count */,
                       float* __restrict__ dw     /* raw -> new_weight */,
                       float* __restrict__ ncb) {
    const int k = blockIdx.x;
    const int c = threadIdx.x;
    const float cnt  = counts[k];
    const float ncnt = (DECAYF * ema_c[k] + (1.f - DECAYF) * cnt + EPSF)
                       / (8.f + (float)K_CODES * EPSF) * 8.f;
    const size_t o = (size_t)k * C_DIM + c;
    const float nw = DECAYF * ema_w[o] + (1.f - DECAYF) * dw[o];
    __syncthreads();  // all raw reads of counts[k] done before the c==0 write
    dw[o]  = nw;
    ncb[o] = nw / ncnt;
    if (c == 0) counts[k] = ncnt;
}

extern "C" void kernel_launch(void* const* d_in, const int* in_sizes, int n_in,
                              void* d_out, int out_size, void* d_ws, size_t ws_size,
                              hipStream_t stream) {
    const float* x     = (const float*)d_in[0];
    const float* cb    = (const float*)d_in[1];
    const float* ema_c = (const float*)d_in[2];
    const float* ema_w = (const float*)d_in[3];
    float* out = (float*)d_out;

    float* qout = out + OFF_QUANT;
    float* ncb  = out + OFF_NCB;
    float* ncnt = out + OFF_NCNT;  // doubles as raw counts accumulator
    float* nw   = out + OFF_NW;    // doubles as raw dw accumulator
    float* idxf = out + OFF_IDX;

    float* cnorm    = (float*)d_ws;            // 8192 floats
    float* loss_arr = cnorm + K_CODES;         // 256 floats

    hipMemsetAsync(ncnt, 0, K_CODES * sizeof(float), stream);
    hipMemsetAsync(nw, 0, (size_t)K_CODES * C_DIM * sizeof(float), stream);
    hipMemsetAsync(loss_arr, 0, 256 * sizeof(float), stream);

    knorm<<<K_CODES / 4, 256, 0, stream>>>(cb, cnorm);
    kargmin<<<N_ROWS / 64, 256, 0, stream>>>(x, cb, cnorm, idxf);
    kquant<<<32768, 256, 0, stream>>>(x, cb, idxf, qout, nw, ncnt, loss_arr);
    kstats<<<1, 256, 0, stream>>>(ncnt, loss_arr, out);
    kfinal<<<K_CODES, C_DIM, 0, stream>>>(ema_c, ema_w, ncnt, nw, ncb);
}

// Round 2
// 3608.976 us; speedup vs baseline: 1.0778x; 1.0778x over previous
//
#include <hip/hip_runtime.h>
#include <hip/hip_bf16.h>
#include <stdint.h>

#define N_ROWS 32768
#define K_CODES 8192
#define C_DIM 256
#define DECAYF 0.95f
#define COMMITF 0.25f
#define EPSF 1e-5f
#define RESC_EPS 0.02f
#define RESC_CAP 4096

// d_out layout (floats), reference return order
#define OFF_QUANT 0
#define OFF_ELOSS 8388608
#define OFF_PERP  8388609
#define OFF_UNIQ  8388610
#define OFF_NCB   8388611
#define OFF_NCNT  10485763
#define OFF_NW    10493955
#define OFF_IDX   12591107

typedef __hip_bfloat16 bf16;
typedef float f32x4 __attribute__((ext_vector_type(4)));
typedef short bf16x8 __attribute__((ext_vector_type(8)));
typedef unsigned long long u64;

#define SWZ(r) ((((r) >> 2) & 7) << 2)

// ---- async global->LDS, 16B per lane ----
#if defined(__has_builtin)
#if __has_builtin(__builtin_amdgcn_global_load_lds)
#define HAVE_GLDS 1
#endif
#endif
#ifdef HAVE_GLDS
#define GLDS16(g, l) __builtin_amdgcn_global_load_lds( \
    (const __attribute__((address_space(1))) void*)(uintptr_t)(g), \
    (__attribute__((address_space(3))) void*)(uint32_t)(uintptr_t)(l), 16, 0, 0)
#else
#define GLDS16(g, l) do { *(float4*)(l) = *(const float4*)(g); } while (0)
#endif

__device__ __forceinline__ uint32_t fkey(float f) {
    uint32_t b = __float_as_uint(f);
    return b ^ ((uint32_t)((int32_t)b >> 31) | 0x80000000u);
}
__device__ __forceinline__ float funkey(uint32_t k) {
    uint32_t b = (k & 0x80000000u) ? (k ^ 0x80000000u) : ~k;
    return __uint_as_float(b);
}
__device__ __forceinline__ void split3(float v, unsigned short& h, unsigned short& m, unsigned short& l) {
    bf16 hb = __float2bfloat16(v);
    float fh = __bfloat162float(hb);
    float r1 = v - fh;
    bf16 mb = __float2bfloat16(r1);
    float fm = __bfloat162float(mb);
    float r2 = r1 - fm;
    bf16 lb = __float2bfloat16(r2);
    h = *(unsigned short*)&hb; m = *(unsigned short*)&mb; l = *(unsigned short*)&lb;
}

// ---------------- codebook row squared-norms ----------------
__global__ void knorm(const float* __restrict__ cb, float* __restrict__ cnorm) {
    const int wid  = threadIdx.x >> 6;
    const int lane = threadIdx.x & 63;
    const int row  = blockIdx.x * 4 + wid;
    const float4 v = *(const float4*)(cb + (size_t)row * C_DIM + lane * 4);
    float s = v.x * v.x + v.y * v.y + v.z * v.z + v.w * v.w;
    #pragma unroll
    for (int off = 32; off; off >>= 1) s += __shfl_down(s, off);
    if (lane == 0) cnorm[row] = s;
}

// ---------------- split codebook into 3 bf16 planes ----------------
__global__ void ksplit_cb(const float* __restrict__ cb, unsigned short* __restrict__ Bsp) {
    const size_t plane = (size_t)K_CODES * C_DIM;
    const size_t i4 = ((size_t)blockIdx.x * 256 + threadIdx.x) * 4;
    const float4 v = *(const float4*)(cb + i4);
    ushort4 h, m, l;
    split3(v.x, h.x, m.x, l.x); split3(v.y, h.y, m.y, l.y);
    split3(v.z, h.z, m.z, l.z); split3(v.w, h.w, m.w, l.w);
    *(ushort4*)(Bsp + i4) = h;
    *(ushort4*)(Bsp + plane + i4) = m;
    *(ushort4*)(Bsp + 2 * plane + i4) = l;
}

// ---------------- transpose x to [n][c] and split into 3 bf16 planes ----------------
__global__ __launch_bounds__(256)
void ksplit_x(const float* __restrict__ x, unsigned short* __restrict__ Asp) {
    __shared__ float xt[64][65];
    const int t = threadIdx.x;
    const int bid = blockIdx.x;        // 8 b * 4 ct * 64 st = 2048
    const int st = bid & 63;
    const int ct = (bid >> 6) & 3;
    const int b  = bid >> 8;
    const float* xb = x + ((size_t)b * C_DIM + ct * 64) * 4096 + st * 64;
    {
        const int s_l = t & 63, c0 = t >> 6;
        #pragma unroll
        for (int cc = 0; cc < 16; ++cc) {
            int c_l = cc * 4 + c0;
            xt[c_l][s_l] = xb[(size_t)c_l * 4096 + s_l];
        }
    }
    __syncthreads();
    const size_t plane = (size_t)N_ROWS * C_DIM;
    const int c2 = (t & 31) * 2;
    const int s0 = t >> 5;
    #pragma unroll
    for (int ww = 0; ww < 8; ++ww) {
        int s_o = ww * 8 + s0;
        float v0 = xt[c2][s_o], v1 = xt[c2 + 1][s_o];
        unsigned short h0, m0_, l0, h1, m1_, l1;
        split3(v0, h0, m0_, l0); split3(v1, h1, m1_, l1);
        size_t off = ((size_t)(b * 4096 + st * 64 + s_o)) * C_DIM + ct * 64 + c2;
        *(ushort2*)(Asp + off)             = make_ushort2(h0, h1);
        *(ushort2*)(Asp + plane + off)     = make_ushort2(m0_, m1_);
        *(ushort2*)(Asp + 2 * plane + off) = make_ushort2(l0, l1);
    }
}

// ---------------- MFMA distance GEMM + per-row top-2 argmin ----------------
// grid 16384: mtile = bid&255 (128 rows), ntile = bid>>8 (128 codes)
__global__ __launch_bounds__(256)
void kargmin_mfma(const unsigned short* __restrict__ Asp, const unsigned short* __restrict__ Bsp,
                  const float* __restrict__ cnorm, u64* __restrict__ wsmin) {
    __shared__ unsigned short As[128 * 64];
    __shared__ unsigned short Bs[128 * 64];
    __shared__ u64 redbuf[128][2][2];

    const int t = threadIdx.x;
    const int lane = t & 63;
    const int wid = t >> 6;
    const int bid = blockIdx.x;
    const int mtile = bid & 255;
    const int ntile = bid >> 8;
    const int m0 = mtile * 128;
    const int n0 = ntile * 128;
    const int wm = (wid >> 1) * 64;
    const int wn = (wid & 1) * 64;

    f32x4 acc[4][4];
    #pragma unroll
    for (int i = 0; i < 4; ++i)
        #pragma unroll
        for (int j = 0; j < 4; ++j) acc[i][j] = (f32x4){0.f, 0.f, 0.f, 0.f};

    const int PA[6] = {0, 0, 0, 1, 1, 2};
    const int PB[6] = {0, 1, 2, 0, 1, 0};

    for (int kt = 0; kt < 24; ++kt) {
        const int seg = kt >> 2;
        const int kk0 = (kt & 3) * 64;
        const unsigned short* Ab = Asp + ((size_t)PA[seg] * N_ROWS + m0) * C_DIM + kk0;
        const unsigned short* Bb = Bsp + ((size_t)PB[seg] * K_CODES + n0) * C_DIM + kk0;
        __syncthreads();
        #pragma unroll
        for (int it = 0; it < 4; ++it) {
            int chunk = it * 256 + t;
            int r = chunk >> 3, kb = (chunk & 7) * 8;
            GLDS16(Ab + (size_t)r * C_DIM + kb, As + chunk * 8);
            GLDS16(Bb + (size_t)r * C_DIM + kb, Bs + chunk * 8);
        }
        __syncthreads();
        #pragma unroll
        for (int kh = 0; kh < 2; ++kh) {
            bf16x8 a[4], b[4];
            #pragma unroll
            for (int i = 0; i < 4; ++i)
                a[i] = *(const bf16x8*)&As[(wm + i * 16 + (lane & 15)) * 64 + kh * 32 + (lane >> 4) * 8];
            #pragma unroll
            for (int j = 0; j < 4; ++j)
                b[j] = *(const bf16x8*)&Bs[(wn + j * 16 + (lane & 15)) * 64 + kh * 32 + (lane >> 4) * 8];
            #pragma unroll
            for (int i = 0; i < 4; ++i)
                #pragma unroll
                for (int j = 0; j < 4; ++j)
                    acc[i][j] = __builtin_amdgcn_mfma_f32_16x16x32_bf16(a[i], b[j], acc[i][j], 0, 0, 0);
        }
    }

    // epilogue: dist = cnorm - 2*dot ; per-row top-2 packed (distkey<<32 | code)
    float cn[4];
    #pragma unroll
    for (int j = 0; j < 4; ++j) cn[j] = cnorm[n0 + wn + j * 16 + (lane & 15)];

    u64 p1[4][4], p2[4][4];
    #pragma unroll
    for (int i = 0; i < 4; ++i)
        #pragma unroll
        for (int r = 0; r < 4; ++r) {
            u64 b1 = ~0ull, b2 = ~0ull;
            #pragma unroll
            for (int j = 0; j < 4; ++j) {
                float dist = fmaf(-2.f, acc[i][j][r], cn[j]);
                u64 pk = ((u64)fkey(dist) << 32) | (unsigned)(n0 + wn + j * 16 + (lane & 15));
                if (pk < b1) { b2 = b1; b1 = pk; }
                else if (pk < b2) b2 = pk;
            }
            p1[i][r] = b1; p2[i][r] = b2;
        }

    #pragma unroll
    for (int off = 1; off < 16; off <<= 1) {
        #pragma unroll
        for (int i = 0; i < 4; ++i)
            #pragma unroll
            for (int r = 0; r < 4; ++r) {
                u64 o1 = __shfl_xor(p1[i][r], off);
                u64 o2 = __shfl_xor(p2[i][r], off);
                u64 lo = p1[i][r] < o1 ? p1[i][r] : o1;
                u64 hi = p1[i][r] < o1 ? o1 : p1[i][r];
                u64 mn2 = p2[i][r] < o2 ? p2[i][r] : o2;
                p1[i][r] = lo;
                p2[i][r] = hi < mn2 ? hi : mn2;
            }
    }
    if ((lane & 15) == 0) {
        const int lg = lane >> 4;
        #pragma unroll
        for (int i = 0; i < 4; ++i)
            #pragma unroll
            for (int r = 0; r < 4; ++r) {
                int rl = wm + i * 16 + lg * 4 + r;
                redbuf[rl][wid & 1][0] = p1[i][r];
                redbuf[rl][wid & 1][1] = p2[i][r];
            }
    }
    __syncthreads();
    if (t < 128) {
        u64 a1 = redbuf[t][0][0], a2 = redbuf[t][0][1];
        u64 b1 = redbuf[t][1][0], b2 = redbuf[t][1][1];
        u64 lo = a1 < b1 ? a1 : b1;
        u64 hi = a1 < b1 ? b1 : a1;
        u64 mn2 = a2 < b2 ? a2 : b2;
        u64 q2 = hi < mn2 ? hi : mn2;
        size_t o = ((size_t)(m0 + t) * 64 + ntile) * 2;
        wsmin[o] = lo; wsmin[o + 1] = q2;
    }
}

// ---------------- combine per-ntile mins; flag near-ties ----------------
__global__ void kcombine(const u64* __restrict__ wsmin, float* __restrict__ idxf,
                         unsigned* __restrict__ rcnt, unsigned* __restrict__ rrows) {
    const int row = blockIdx.x * 256 + threadIdx.x;
    const u64* p = wsmin + (size_t)row * 128;
    u64 m1 = ~0ull, m2 = ~0ull;
    for (int i = 0; i < 128; i += 2) {
        u64 a = p[i], b = p[i + 1];
        u64 lo = a < m1 ? a : m1;
        u64 hi = a < m1 ? m1 : a;
        u64 c = m2 < b ? m2 : b;
        m1 = lo;
        m2 = hi < c ? hi : c;
    }
    idxf[row] = (float)(unsigned)(m1 & 0xffffffffu);
    float d1 = funkey((uint32_t)(m1 >> 32));
    float d2 = funkey((uint32_t)(m2 >> 32));
    if (d2 - d1 < RESC_EPS) {
        unsigned slot = atomicAdd(rcnt, 1u);
        if (slot < RESC_CAP) rrows[slot] = (unsigned)row;
    }
}

// ---------------- exact fp32 re-score for near-tie rows ----------------
__global__ __launch_bounds__(256)
void krescue(const float* __restrict__ x, const float* __restrict__ cb,
             const float* __restrict__ cnorm, const unsigned* __restrict__ rcnt,
             const unsigned* __restrict__ rrows, float* __restrict__ idxf) {
    __shared__ float xs[256];
    __shared__ u64 red[4];
    unsigned cnt = *rcnt; if (cnt > RESC_CAP) cnt = RESC_CAP;
    for (unsigned li = blockIdx.x; li < cnt; li += gridDim.x) {
        const int row = (int)rrows[li];
        const int b = row >> 12, s = row & 4095;
        xs[threadIdx.x] = x[((size_t)b * C_DIM + threadIdx.x) * 4096 + s];
        __syncthreads();
        u64 best = ~0ull;
        for (int k0 = 0; k0 < K_CODES; k0 += 256) {
            const int k = k0 + threadIdx.x;
            const float* cr = cb + (size_t)k * C_DIM;
            float dot = 0.f;
            #pragma unroll 8
            for (int c = 0; c < C_DIM; ++c) dot = fmaf(xs[c], cr[c], dot);
            float dist = fmaf(-2.f, dot, cnorm[k]);
            u64 pk = ((u64)fkey(dist) << 32) | (unsigned)k;
            if (pk < best) best = pk;
        }
        #pragma unroll
        for (int off = 32; off; off >>= 1) {
            u64 o = __shfl_down(best, off);
            if (o < best) best = o;
        }
        if ((threadIdx.x & 63) == 0) red[threadIdx.x >> 6] = best;
        __syncthreads();
        if (threadIdx.x == 0) {
            u64 r0 = red[0];
            #pragma unroll
            for (int w = 1; w < 4; ++w) if (red[w] < r0) r0 = red[w];
            idxf[row] = (float)(unsigned)(r0 & 0xffffffffu);
        }
        __syncthreads();
    }
}

// ---------------- fallback fp32 argmin (round-1 kernel) ----------------
__launch_bounds__(256, 1)
__global__ void kargmin_fp32(const float* __restrict__ x, const float* __restrict__ cb,
                             const float* __restrict__ cnorm, float* __restrict__ idxf) {
    __shared__ float xs[64][256];
    __shared__ float es[64][256];
    const int t  = threadIdx.x;
    const int n0 = blockIdx.x * 64;
    const int b  = n0 >> 12;
    const int s0 = n0 & 4095;
    {
        const int r  = t & 63;
        const int c0 = t >> 6;
        const float* xb = x + (size_t)b * C_DIM * 4096 + s0 + r;
        const int sw = SWZ(r);
        #pragma unroll 8
        for (int cc = 0; cc < 64; ++cc) {
            int c = cc * 4 + c0;
            xs[r][c ^ sw] = xb[(size_t)c * 4096];
        }
    }
    const int mg  = t >> 4;
    const int ng  = t & 15;
    const int m0  = mg * 4;
    const int nn0 = ng * 4;
    const int swm = SWZ(m0);
    const int swn = SWZ(nn0);
    float minv[4] = {1e30f, 1e30f, 1e30f, 1e30f};
    int   mini[4] = {0, 0, 0, 0};
    for (int k0 = 0; k0 < K_CODES; k0 += 64) {
        __syncthreads();
        {
            const int lane = t & 63;
            const int cw   = t >> 6;
            #pragma unroll
            for (int p = 0; p < 16; ++p) {
                int code = p * 4 + cw;
                float4 v = *(const float4*)(cb + (size_t)(k0 + code) * C_DIM + lane * 4);
                *(float4*)&es[code][(lane * 4) ^ SWZ(code)] = v;
            }
        }
        float cn[4];
        #pragma unroll
        for (int j = 0; j < 4; ++j) cn[j] = cnorm[k0 + nn0 + j];
        __syncthreads();
        float acc[4][4];
        #pragma unroll
        for (int i = 0; i < 4; ++i)
            #pragma unroll
            for (int j = 0; j < 4; ++j) acc[i][j] = 0.f;
        #pragma unroll 4
        for (int c = 0; c < C_DIM; c += 4) {
            float4 xa[4], eb[4];
            #pragma unroll
            for (int i = 0; i < 4; ++i) xa[i] = *(const float4*)&xs[m0 + i][c ^ swm];
            #pragma unroll
            for (int j = 0; j < 4; ++j) eb[j] = *(const float4*)&es[nn0 + j][c ^ swn];
            #pragma unroll
            for (int i = 0; i < 4; ++i)
                #pragma unroll
                for (int j = 0; j < 4; ++j)
                    acc[i][j] += xa[i].x * eb[j].x + xa[i].y * eb[j].y +
                                 xa[i].z * eb[j].z + xa[i].w * eb[j].w;
        }
        #pragma unroll
        for (int j = 0; j < 4; ++j) {
            const int kg = k0 + nn0 + j;
            #pragma unroll
            for (int i = 0; i < 4; ++i) {
                float dist = fmaf(-2.f, acc[i][j], cn[j]);
                if (dist < minv[i]) { minv[i] = dist; mini[i] = kg; }
            }
        }
    }
    #pragma unroll
    for (int off = 1; off < 16; off <<= 1) {
        #pragma unroll
        for (int i = 0; i < 4; ++i) {
            float ov = __shfl_xor(minv[i], off);
            int   oi = __shfl_xor(mini[i], off);
            if (ov < minv[i] || (ov == minv[i] && oi < mini[i])) { minv[i] = ov; mini[i] = oi; }
        }
    }
    if (ng == 0) {
        #pragma unroll
        for (int i = 0; i < 4; ++i) idxf[n0 + m0 + i] = (float)mini[i];
    }
}

// ---------------- quantize + e_loss partials + segment sums ----------------
__global__ void kquant(const float* __restrict__ x, const float* __restrict__ cb,
                       const float* __restrict__ idxf, float* __restrict__ qout,
                       float* __restrict__ dw, float* __restrict__ counts,
                       float* __restrict__ loss_arr) {
    const int t   = threadIdx.x;
    const int bid = blockIdx.x;
    const int sc  = bid & 15;
    const int c   = (bid >> 4) & 255;
    const int b   = bid >> 12;
    const int s   = sc * 256 + t;
    const int n   = b * 4096 + s;
    const int k   = (int)idxf[n];

    const size_t xoff = ((size_t)b * C_DIM + c) * 4096 + s;
    const float xv = x[xoff];
    const float q  = cb[(size_t)k * C_DIM + c];
    qout[xoff] = xv + (q - xv);
    atomicAdd(&dw[(size_t)k * C_DIM + c], xv);
    if (c == 0) atomicAdd(&counts[k], 1.0f);

    float d = q - xv;
    float p = d * d;
    #pragma unroll
    for (int off = 32; off; off >>= 1) p += __shfl_down(p, off);
    __shared__ float ps[4];
    if ((t & 63) == 0) ps[t >> 6] = p;
    __syncthreads();
    if (t == 0) atomicAdd(&loss_arr[bid & 255], ps[0] + ps[1] + ps[2] + ps[3]);
}

// ---------------- perplexity / unique / e_loss ----------------
__global__ void kstats(const float* __restrict__ counts, const float* __restrict__ loss_arr,
                       float* __restrict__ out) {
    const int t = threadIdx.x;
    float nz = 0.f, s = 0.f;
    for (int k = t; k < K_CODES; k += 256) {
        float cnt = counts[k];
        if (cnt != 0.f) nz += 1.f;
        float p = cnt * (1.f / 32768.f);
        s += p * logf(p + 1e-10f);
    }
    float ls = loss_arr[t];
    #pragma unroll
    for (int off = 32; off; off >>= 1) {
        s  += __shfl_down(s, off);
        nz += __shfl_down(nz, off);
        ls += __shfl_down(ls, off);
    }
    __shared__ float ss[4], zz[4], ll[4];
    const int wid = t >> 6, lane = t & 63;
    if (lane == 0) { ss[wid] = s; zz[wid] = nz; ll[wid] = ls; }
    __syncthreads();
    if (t == 0) {
        float st = ss[0] + ss[1] + ss[2] + ss[3];
        float zt = zz[0] + zz[1] + zz[2] + zz[3];
        float lt = ll[0] + ll[1] + ll[2] + ll[3];
        out[OFF_ELOSS] = COMMITF * lt / 8388608.f;
        out[OFF_PERP]  = expf(-st);
        out[OFF_UNIQ]  = zt;
    }
}

// ---------------- EMA finalize ----------------
__global__ void kfinal(const float* __restrict__ ema_c, const float* __restrict__ ema_w,
                       float* __restrict__ counts, float* __restrict__ dw,
                       float* __restrict__ ncb) {
    const int k = blockIdx.x;
    const int c = threadIdx.x;
    const float cnt  = counts[k];
    const float ncnt = (DECAYF * ema_c[k] + (1.f - DECAYF) * cnt + EPSF)
                       / (8.f + (float)K_CODES * EPSF) * 8.f;
    const size_t o = (size_t)k * C_DIM + c;
    const float nw = DECAYF * ema_w[o] + (1.f - DECAYF) * dw[o];
    __syncthreads();
    dw[o]  = nw;
    ncb[o] = nw / ncnt;
    if (c == 0) counts[k] = ncnt;
}

extern "C" void kernel_launch(void* const* d_in, const int* in_sizes, int n_in,
                              void* d_out, int out_size, void* d_ws, size_t ws_size,
                              hipStream_t stream) {
    const float* x     = (const float*)d_in[0];
    const float* cb    = (const float*)d_in[1];
    const float* ema_c = (const float*)d_in[2];
    const float* ema_w = (const float*)d_in[3];
    float* out = (float*)d_out;

    float* qout = out + OFF_QUANT;
    float* ncb  = out + OFF_NCB;
    float* ncnt = out + OFF_NCNT;
    float* nw   = out + OFF_NW;
    float* idxf = out + OFF_IDX;

    const size_t planeA = (size_t)3 * N_ROWS * C_DIM;   // bf16 elems
    const size_t planeB = (size_t)3 * K_CODES * C_DIM;
    const size_t need = (planeA + planeB) * 2 + (size_t)K_CODES * 4 + 256 * 4 + 4 + RESC_CAP * 4;
    const bool use_mfma = ws_size >= need;

    hipMemsetAsync(ncnt, 0, K_CODES * sizeof(float), stream);
    hipMemsetAsync(nw, 0, (size_t)K_CODES * C_DIM * sizeof(float), stream);

    if (use_mfma) {
        unsigned short* Asp = (unsigned short*)d_ws;
        unsigned short* Bsp = Asp + planeA;
        float* cnorm = (float*)(Bsp + planeB);
        float* loss_arr = cnorm + K_CODES;
        unsigned* rcnt = (unsigned*)(loss_arr + 256);
        unsigned* rrows = rcnt + 1;
        u64* wsmin = (u64*)(out + OFF_QUANT);   // 33.5 MB, consumed before kquant writes qout

        hipMemsetAsync(loss_arr, 0, 256 * sizeof(float), stream);
        hipMemsetAsync(rcnt, 0, sizeof(unsigned), stream);

        knorm<<<K_CODES / 4, 256, 0, stream>>>(cb, cnorm);
        ksplit_cb<<<(K_CODES * C_DIM / 4) / 256, 256, 0, stream>>>(cb, Bsp);
        ksplit_x<<<2048, 256, 0, stream>>>(x, Asp);
        kargmin_mfma<<<16384, 256, 0, stream>>>(Asp, Bsp, cnorm, wsmin);
        kcombine<<<N_ROWS / 256, 256, 0, stream>>>(wsmin, idxf, rcnt, rrows);
        krescue<<<128, 256, 0, stream>>>(x, cb, cnorm, rcnt, rrows, idxf);
        kquant<<<32768, 256, 0, stream>>>(x, cb, idxf, qout, nw, ncnt, loss_arr);
        kstats<<<1, 256, 0, stream>>>(ncnt, loss_arr, out);
        kfinal<<<K_CODES, C_DIM, 0, stream>>>(ema_c, ema_w, ncnt, nw, ncb);
    } else {
        float* cnorm = (float*)d_ws;
        float* loss_arr = cnorm + K_CODES;
        hipMemsetAsync(loss_arr, 0, 256 * sizeof(float), stream);
        knorm<<<K_CODES / 4, 256, 0, stream>>>(cb, cnorm);
        kargmin_fp32<<<N_ROWS / 64, 256, 0, stream>>>(x, cb, cnorm, idxf);
        kquant<<<32768, 256, 0, stream>>>(x, cb, idxf, qout, nw, ncnt, loss_arr);
        kstats<<<1, 256, 0, stream>>>(ncnt, loss_arr, out);
        kfinal<<<K_CODES, C_DIM, 0, stream>>>(ema_c, ema_w, ncnt, nw, ncb);
    }
}

// Round 3
// 2820.683 us; speedup vs baseline: 1.3791x; 1.2795x over previous
//
#include <hip/hip_runtime.h>
#include <hip/hip_bf16.h>
#include <stdint.h>

#define N_ROWS 32768
#define K_CODES 8192
#define C_DIM 256
#define DECAYF 0.95f
#define COMMITF 0.25f
#define EPSF 1e-5f
#define RESC_EPS 0.02f
#define RESC_CAP 4096

// d_out layout (floats), reference return order
#define OFF_QUANT 0
#define OFF_ELOSS 8388608
#define OFF_PERP  8388609
#define OFF_UNIQ  8388610
#define OFF_NCB   8388611
#define OFF_NCNT  10485763
#define OFF_NW    10493955
#define OFF_IDX   12591107

typedef __hip_bfloat16 bf16;
typedef float f32x4 __attribute__((ext_vector_type(4)));
typedef short bf16x8 __attribute__((ext_vector_type(8)));
typedef unsigned long long u64;

#define SWZ(r) ((((r) >> 2) & 7) << 2)

#if defined(__has_builtin)
#if __has_builtin(__builtin_amdgcn_global_load_lds)
#define HAVE_GLDS 1
#endif
#endif
#ifdef HAVE_GLDS
#define GLDS16(g, l) __builtin_amdgcn_global_load_lds( \
    (const __attribute__((address_space(1))) void*)(uintptr_t)(g), \
    (__attribute__((address_space(3))) void*)(uint32_t)(uintptr_t)(l), 16, 0, 0)
#else
#define GLDS16(g, l) do { *(float4*)(l) = *(const float4*)(g); } while (0)
#endif

__device__ __forceinline__ uint32_t fkey(float f) {
    uint32_t b = __float_as_uint(f);
    return b ^ ((uint32_t)((int32_t)b >> 31) | 0x80000000u);
}
__device__ __forceinline__ float funkey(uint32_t k) {
    uint32_t b = (k & 0x80000000u) ? (k ^ 0x80000000u) : ~k;
    return __uint_as_float(b);
}
__device__ __forceinline__ void split2(float v, unsigned short& h, unsigned short& m) {
    bf16 hb = __float2bfloat16(v);
    float fh = __bfloat162float(hb);
    bf16 mb = __float2bfloat16(v - fh);
    h = *(unsigned short*)&hb; m = *(unsigned short*)&mb;
}

// ---------------- codebook row squared-norms ----------------
__global__ void knorm(const float* __restrict__ cb, float* __restrict__ cnorm) {
    const int wid  = threadIdx.x >> 6;
    const int lane = threadIdx.x & 63;
    const int row  = blockIdx.x * 4 + wid;
    const float4 v = *(const float4*)(cb + (size_t)row * C_DIM + lane * 4);
    float s = v.x * v.x + v.y * v.y + v.z * v.z + v.w * v.w;
    #pragma unroll
    for (int off = 32; off; off >>= 1) s += __shfl_down(s, off);
    if (lane == 0) cnorm[row] = s;
}

// ---------------- split codebook into 2 bf16 planes ----------------
__global__ void ksplit_cb(const float* __restrict__ cb, unsigned short* __restrict__ Bsp) {
    const size_t plane = (size_t)K_CODES * C_DIM;
    const size_t i4 = ((size_t)blockIdx.x * 256 + threadIdx.x) * 4;
    const float4 v = *(const float4*)(cb + i4);
    ushort4 h, m;
    split2(v.x, h.x, m.x); split2(v.y, h.y, m.y);
    split2(v.z, h.z, m.z); split2(v.w, h.w, m.w);
    *(ushort4*)(Bsp + i4) = h;
    *(ushort4*)(Bsp + plane + i4) = m;
}

// ---------------- transpose x to [n][c] and split into 2 bf16 planes ----------------
__global__ __launch_bounds__(256)
void ksplit_x(const float* __restrict__ x, unsigned short* __restrict__ Asp) {
    __shared__ float xt[64][65];
    const int t = threadIdx.x;
    const int bid = blockIdx.x;        // 8 b * 4 ct * 64 st = 2048
    const int st = bid & 63;
    const int ct = (bid >> 6) & 3;
    const int b  = bid >> 8;
    const float* xb = x + ((size_t)b * C_DIM + ct * 64) * 4096 + st * 64;
    {
        const int s_l = t & 63, c0 = t >> 6;
        #pragma unroll
        for (int cc = 0; cc < 16; ++cc) {
            int c_l = cc * 4 + c0;
            xt[c_l][s_l] = xb[(size_t)c_l * 4096 + s_l];
        }
    }
    __syncthreads();
    const size_t plane = (size_t)N_ROWS * C_DIM;
    const int c2 = (t & 31) * 2;
    const int s0 = t >> 5;
    #pragma unroll
    for (int ww = 0; ww < 8; ++ww) {
        int s_o = ww * 8 + s0;
        float v0 = xt[c2][s_o], v1 = xt[c2 + 1][s_o];
        unsigned short h0, m0_, h1, m1_;
        split2(v0, h0, m0_); split2(v1, h1, m1_);
        size_t off = ((size_t)(b * 4096 + st * 64 + s_o)) * C_DIM + ct * 64 + c2;
        *(ushort2*)(Asp + off)         = make_ushort2(h0, h1);
        *(ushort2*)(Asp + plane + off) = make_ushort2(m0_, m1_);
    }
}

// ---------------- MFMA distance GEMM + per-row top-2 argmin ----------------
// grid 16384: mtile = bid&255 (128 rows), ntile = bid>>8 (128 codes)
// LDS tiles hold the SWIZZLED layout: slot' = slot ^ (row&7); the staging
// reads the inverse-permuted global column so linear global_load_lds writes
// land swizzled; ds_read applies the same XOR (rule #21: both-sides).
__global__ __launch_bounds__(256)
void kargmin_mfma(const unsigned short* __restrict__ Asp, const unsigned short* __restrict__ Bsp,
                  const float* __restrict__ cnorm, u64* __restrict__ wsmin) {
    __shared__ unsigned short As[128 * 64];
    __shared__ unsigned short Bs[128 * 64];

    const int t = threadIdx.x;
    const int lane = t & 63;
    const int wid = t >> 6;
    const int bid = blockIdx.x;
    const int mtile = bid & 255;
    const int ntile = bid >> 8;
    const int m0 = mtile * 128;
    const int n0 = ntile * 128;
    const int wm = (wid >> 1) * 64;
    const int wn = (wid & 1) * 64;
    const int lm = lane & 15;
    const int lh = lane >> 4;
    const int l7 = lane & 7;

    f32x4 acc[4][4];
    #pragma unroll
    for (int i = 0; i < 4; ++i)
        #pragma unroll
        for (int j = 0; j < 4; ++j) acc[i][j] = (f32x4){0.f, 0.f, 0.f, 0.f};

    const int PA[4] = {0, 0, 1, 1};
    const int PB[4] = {0, 1, 0, 1};

    // staging-side per-thread constants
    const int sr = t >> 3;               // row 0..127  (chunk = it*256+t -> r = (it*32)+sr? no)
    // NOTE: chunk = it*256 + t; r = chunk>>3 = it*32 + (t>>3); slot = t&7

    for (int kt = 0; kt < 16; ++kt) {
        const int seg = kt >> 2;
        const int kk0 = (kt & 3) * 64;
        const unsigned short* Ab = Asp + ((size_t)PA[seg] * N_ROWS + m0) * C_DIM + kk0;
        const unsigned short* Bb = Bsp + ((size_t)PB[seg] * K_CODES + n0) * C_DIM + kk0;
        __syncthreads();
        #pragma unroll
        for (int it = 0; it < 4; ++it) {
            const int chunk = it * 256 + t;
            const int r = it * 32 + sr;
            const int gslot = (t & 7) ^ (r & 7);
            GLDS16(Ab + (size_t)r * C_DIM + gslot * 8, As + chunk * 8);
            GLDS16(Bb + (size_t)r * C_DIM + gslot * 8, Bs + chunk * 8);
        }
        __syncthreads();
        #pragma unroll
        for (int kh = 0; kh < 2; ++kh) {
            const int sw = (((kh * 4 + lh) ^ l7)) * 8;   // swizzled 8-short slot offset
            bf16x8 a[4], b[4];
            #pragma unroll
            for (int i = 0; i < 4; ++i)
                a[i] = *(const bf16x8*)&As[(wm + i * 16 + lm) * 64 + sw];
            #pragma unroll
            for (int j = 0; j < 4; ++j)
                b[j] = *(const bf16x8*)&Bs[(wn + j * 16 + lm) * 64 + sw];
            #pragma unroll
            for (int i = 0; i < 4; ++i)
                #pragma unroll
                for (int j = 0; j < 4; ++j)
                    acc[i][j] = __builtin_amdgcn_mfma_f32_16x16x32_bf16(a[i], b[j], acc[i][j], 0, 0, 0);
        }
    }

    // epilogue: dist = cnorm - 2*dot ; per-row top-2 packed (distkey<<32 | code)
    float cn[4];
    #pragma unroll
    for (int j = 0; j < 4; ++j) cn[j] = cnorm[n0 + wn + j * 16 + lm];

    u64 p1[4][4], p2[4][4];
    #pragma unroll
    for (int i = 0; i < 4; ++i)
        #pragma unroll
        for (int r = 0; r < 4; ++r) {
            u64 b1 = ~0ull, b2 = ~0ull;
            #pragma unroll
            for (int j = 0; j < 4; ++j) {
                float dist = fmaf(-2.f, acc[i][j][r], cn[j]);
                u64 pk = ((u64)fkey(dist) << 32) | (unsigned)(n0 + wn + j * 16 + lm);
                if (pk < b1) { b2 = b1; b1 = pk; }
                else if (pk < b2) b2 = pk;
            }
            p1[i][r] = b1; p2[i][r] = b2;
        }

    #pragma unroll
    for (int off = 1; off < 16; off <<= 1) {
        #pragma unroll
        for (int i = 0; i < 4; ++i)
            #pragma unroll
            for (int r = 0; r < 4; ++r) {
                u64 o1 = __shfl_xor(p1[i][r], off);
                u64 o2 = __shfl_xor(p2[i][r], off);
                u64 lo = p1[i][r] < o1 ? p1[i][r] : o1;
                u64 hi = p1[i][r] < o1 ? o1 : p1[i][r];
                u64 mn2 = p2[i][r] < o2 ? p2[i][r] : o2;
                p1[i][r] = lo;
                p2[i][r] = hi < mn2 ? hi : mn2;
            }
    }

    u64* redbuf = (u64*)As;   // reuse A tile LDS (done with MFMA reads)
    __syncthreads();
    if (lm == 0) {
        #pragma unroll
        for (int i = 0; i < 4; ++i)
            #pragma unroll
            for (int r = 0; r < 4; ++r) {
                int rl = wm + i * 16 + lh * 4 + r;
                redbuf[rl * 4 + (wid & 1) * 2 + 0] = p1[i][r];
                redbuf[rl * 4 + (wid & 1) * 2 + 1] = p2[i][r];
            }
    }
    __syncthreads();
    if (t < 128) {
        u64 a1 = redbuf[t * 4 + 0], a2 = redbuf[t * 4 + 1];
        u64 b1 = redbuf[t * 4 + 2], b2 = redbuf[t * 4 + 3];
        u64 lo = a1 < b1 ? a1 : b1;
        u64 hi = a1 < b1 ? b1 : a1;
        u64 mn2 = a2 < b2 ? a2 : b2;
        u64 q2 = hi < mn2 ? hi : mn2;
        size_t o = ((size_t)(m0 + t) * 64 + ntile) * 2;
        wsmin[o] = lo; wsmin[o + 1] = q2;
    }
}

// ---------------- combine per-ntile mins; flag near-ties ----------------
__global__ void kcombine(const u64* __restrict__ wsmin, float* __restrict__ idxf,
                         unsigned* __restrict__ rcnt, unsigned* __restrict__ rrows) {
    const int row = blockIdx.x * 256 + threadIdx.x;
    const u64* p = wsmin + (size_t)row * 128;
    u64 m1 = ~0ull, m2 = ~0ull;
    for (int i = 0; i < 128; i += 2) {
        u64 a = p[i], b = p[i + 1];
        u64 lo = a < m1 ? a : m1;
        u64 hi = a < m1 ? m1 : a;
        u64 c = m2 < b ? m2 : b;
        m1 = lo;
        m2 = hi < c ? hi : c;
    }
    idxf[row] = (float)(unsigned)(m1 & 0xffffffffu);
    float d1 = funkey((uint32_t)(m1 >> 32));
    float d2 = funkey((uint32_t)(m2 >> 32));
    if (d2 - d1 < RESC_EPS) {
        unsigned slot = atomicAdd(rcnt, 1u);
        if (slot < RESC_CAP) rrows[slot] = (unsigned)row;
    }
}

// ---------------- exact fp32 re-score for near-tie rows ----------------
__global__ __launch_bounds__(256)
void krescue(const float* __restrict__ x, const float* __restrict__ cb,
             const float* __restrict__ cnorm, const unsigned* __restrict__ rcnt,
             const unsigned* __restrict__ rrows, float* __restrict__ idxf) {
    __shared__ float xs[256];
    __shared__ u64 red[4];
    unsigned cnt = *rcnt; if (cnt > RESC_CAP) cnt = RESC_CAP;
    for (unsigned li = blockIdx.x; li < cnt; li += gridDim.x) {
        const int row = (int)rrows[li];
        const int b = row >> 12, s = row & 4095;
        xs[threadIdx.x] = x[((size_t)b * C_DIM + threadIdx.x) * 4096 + s];
        __syncthreads();
        u64 best = ~0ull;
        for (int k0 = 0; k0 < K_CODES; k0 += 256) {
            const int k = k0 + threadIdx.x;
            const float* cr = cb + (size_t)k * C_DIM;
            float dot = 0.f;
            #pragma unroll 8
            for (int c = 0; c < C_DIM; ++c) dot = fmaf(xs[c], cr[c], dot);
            float dist = fmaf(-2.f, dot, cnorm[k]);
            u64 pk = ((u64)fkey(dist) << 32) | (unsigned)k;
            if (pk < best) best = pk;
        }
        #pragma unroll
        for (int off = 32; off; off >>= 1) {
            u64 o = __shfl_down(best, off);
            if (o < best) best = o;
        }
        if ((threadIdx.x & 63) == 0) red[threadIdx.x >> 6] = best;
        __syncthreads();
        if (threadIdx.x == 0) {
            u64 r0 = red[0];
            #pragma unroll
            for (int w = 1; w < 4; ++w) if (red[w] < r0) r0 = red[w];
            idxf[row] = (float)(unsigned)(r0 & 0xffffffffu);
        }
        __syncthreads();
    }
}

// ---------------- fallback fp32 argmin (round-1 kernel) ----------------
__launch_bounds__(256, 1)
__global__ void kargmin_fp32(const float* __restrict__ x, const float* __restrict__ cb,
                             const float* __restrict__ cnorm, float* __restrict__ idxf) {
    __shared__ float xs[64][256];
    __shared__ float es[64][256];
    const int t  = threadIdx.x;
    const int n0 = blockIdx.x * 64;
    const int b  = n0 >> 12;
    const int s0 = n0 & 4095;
    {
        const int r  = t & 63;
        const int c0 = t >> 6;
        const float* xb = x + (size_t)b * C_DIM * 4096 + s0 + r;
        const int sw = SWZ(r);
        #pragma unroll 8
        for (int cc = 0; cc < 64; ++cc) {
            int c = cc * 4 + c0;
            xs[r][c ^ sw] = xb[(size_t)c * 4096];
        }
    }
    const int mg  = t >> 4;
    const int ng  = t & 15;
    const int m0  = mg * 4;
    const int nn0 = ng * 4;
    const int swm = SWZ(m0);
    const int swn = SWZ(nn0);
    float minv[4] = {1e30f, 1e30f, 1e30f, 1e30f};
    int   mini[4] = {0, 0, 0, 0};
    for (int k0 = 0; k0 < K_CODES; k0 += 64) {
        __syncthreads();
        {
            const int lane = t & 63;
            const int cw   = t >> 6;
            #pragma unroll
            for (int p = 0; p < 16; ++p) {
                int code = p * 4 + cw;
                float4 v = *(const float4*)(cb + (size_t)(k0 + code) * C_DIM + lane * 4);
                *(float4*)&es[code][(lane * 4) ^ SWZ(code)] = v;
            }
        }
        float cn[4];
        #pragma unroll
        for (int j = 0; j < 4; ++j) cn[j] = cnorm[k0 + nn0 + j];
        __syncthreads();
        float acc[4][4];
        #pragma unroll
        for (int i = 0; i < 4; ++i)
            #pragma unroll
            for (int j = 0; j < 4; ++j) acc[i][j] = 0.f;
        #pragma unroll 4
        for (int c = 0; c < C_DIM; c += 4) {
            float4 xa[4], eb[4];
            #pragma unroll
            for (int i = 0; i < 4; ++i) xa[i] = *(const float4*)&xs[m0 + i][c ^ swm];
            #pragma unroll
            for (int j = 0; j < 4; ++j) eb[j] = *(const float4*)&es[nn0 + j][c ^ swn];
            #pragma unroll
            for (int i = 0; i < 4; ++i)
                #pragma unroll
                for (int j = 0; j < 4; ++j)
                    acc[i][j] += xa[i].x * eb[j].x + xa[i].y * eb[j].y +
                                 xa[i].z * eb[j].z + xa[i].w * eb[j].w;
        }
        #pragma unroll
        for (int j = 0; j < 4; ++j) {
            const int kg = k0 + nn0 + j;
            #pragma unroll
            for (int i = 0; i < 4; ++i) {
                float dist = fmaf(-2.f, acc[i][j], cn[j]);
                if (dist < minv[i]) { minv[i] = dist; mini[i] = kg; }
            }
        }
    }
    #pragma unroll
    for (int off = 1; off < 16; off <<= 1) {
        #pragma unroll
        for (int i = 0; i < 4; ++i) {
            float ov = __shfl_xor(minv[i], off);
            int   oi = __shfl_xor(mini[i], off);
            if (ov < minv[i] || (ov == minv[i] && oi < mini[i])) { minv[i] = ov; mini[i] = oi; }
        }
    }
    if (ng == 0) {
        #pragma unroll
        for (int i = 0; i < 4; ++i) idxf[n0 + m0 + i] = (float)mini[i];
    }
}

// ---------------- quantize + e_loss partials + segment sums ----------------
__global__ void kquant(const float* __restrict__ x, const float* __restrict__ cb,
                       const float* __restrict__ idxf, float* __restrict__ qout,
                       float* __restrict__ dw, float* __restrict__ counts,
                       float* __restrict__ loss_arr) {
    const int t   = threadIdx.x;
    const int bid = blockIdx.x;
    const int sc  = bid & 15;
    const int c   = (bid >> 4) & 255;
    const int b   = bid >> 12;
    const int s   = sc * 256 + t;
    const int n   = b * 4096 + s;
    const int k   = (int)idxf[n];

    const size_t xoff = ((size_t)b * C_DIM + c) * 4096 + s;
    const float xv = x[xoff];
    const float q  = cb[(size_t)k * C_DIM + c];
    qout[xoff] = xv + (q - xv);
    atomicAdd(&dw[(size_t)k * C_DIM + c], xv);
    if (c == 0) atomicAdd(&counts[k], 1.0f);

    float d = q - xv;
    float p = d * d;
    #pragma unroll
    for (int off = 32; off; off >>= 1) p += __shfl_down(p, off);
    __shared__ float ps[4];
    if ((t & 63) == 0) ps[t >> 6] = p;
    __syncthreads();
    if (t == 0) atomicAdd(&loss_arr[bid & 255], ps[0] + ps[1] + ps[2] + ps[3]);
}

// ---------------- perplexity / unique / e_loss ----------------
__global__ void kstats(const float* __restrict__ counts, const float* __restrict__ loss_arr,
                       float* __restrict__ out) {
    const int t = threadIdx.x;
    float nz = 0.f, s = 0.f;
    for (int k = t; k < K_CODES; k += 256) {
        float cnt = counts[k];
        if (cnt != 0.f) nz += 1.f;
        float p = cnt * (1.f / 32768.f);
        s += p * logf(p + 1e-10f);
    }
    float ls = loss_arr[t];
    #pragma unroll
    for (int off = 32; off; off >>= 1) {
        s  += __shfl_down(s, off);
        nz += __shfl_down(nz, off);
        ls += __shfl_down(ls, off);
    }
    __shared__ float ss[4], zz[4], ll[4];
    const int wid = t >> 6, lane = t & 63;
    if (lane == 0) { ss[wid] = s; zz[wid] = nz; ll[wid] = ls; }
    __syncthreads();
    if (t == 0) {
        float st = ss[0] + ss[1] + ss[2] + ss[3];
        float zt = zz[0] + zz[1] + zz[2] + zz[3];
        float lt = ll[0] + ll[1] + ll[2] + ll[3];
        out[OFF_ELOSS] = COMMITF * lt / 8388608.f;
        out[OFF_PERP]  = expf(-st);
        out[OFF_UNIQ]  = zt;
    }
}

// ---------------- EMA finalize ----------------
__global__ void kfinal(const float* __restrict__ ema_c, const float* __restrict__ ema_w,
                       float* __restrict__ counts, float* __restrict__ dw,
                       float* __restrict__ ncb) {
    const int k = blockIdx.x;
    const int c = threadIdx.x;
    const float cnt  = counts[k];
    const float ncnt = (DECAYF * ema_c[k] + (1.f - DECAYF) * cnt + EPSF)
                       / (8.f + (float)K_CODES * EPSF) * 8.f;
    const size_t o = (size_t)k * C_DIM + c;
    const float nw = DECAYF * ema_w[o] + (1.f - DECAYF) * dw[o];
    __syncthreads();
    dw[o]  = nw;
    ncb[o] = nw / ncnt;
    if (c == 0) counts[k] = ncnt;
}

extern "C" void kernel_launch(void* const* d_in, const int* in_sizes, int n_in,
                              void* d_out, int out_size, void* d_ws, size_t ws_size,
                              hipStream_t stream) {
    const float* x     = (const float*)d_in[0];
    const float* cb    = (const float*)d_in[1];
    const float* ema_c = (const float*)d_in[2];
    const float* ema_w = (const float*)d_in[3];
    float* out = (float*)d_out;

    float* qout = out + OFF_QUANT;
    float* ncb  = out + OFF_NCB;
    float* ncnt = out + OFF_NCNT;
    float* nw   = out + OFF_NW;
    float* idxf = out + OFF_IDX;

    const size_t planeA = (size_t)2 * N_ROWS * C_DIM;   // bf16 elems (h,m)
    const size_t planeB = (size_t)2 * K_CODES * C_DIM;
    const size_t need = (planeA + planeB) * 2 + (size_t)K_CODES * 4 + 256 * 4 + 4 + RESC_CAP * 4;
    const bool use_mfma = ws_size >= need;

    hipMemsetAsync(ncnt, 0, K_CODES * sizeof(float), stream);
    hipMemsetAsync(nw, 0, (size_t)K_CODES * C_DIM * sizeof(float), stream);

    if (use_mfma) {
        unsigned short* Asp = (unsigned short*)d_ws;
        unsigned short* Bsp = Asp + planeA;
        float* cnorm = (float*)(Bsp + planeB);
        float* loss_arr = cnorm + K_CODES;
        unsigned* rcnt = (unsigned*)(loss_arr + 256);
        unsigned* rrows = rcnt + 1;
        u64* wsmin = (u64*)(out + OFF_QUANT);   // 33.5 MB, consumed before kquant writes qout

        hipMemsetAsync(loss_arr, 0, 256 * sizeof(float), stream);
        hipMemsetAsync(rcnt, 0, sizeof(unsigned), stream);

        knorm<<<K_CODES / 4, 256, 0, stream>>>(cb, cnorm);
        ksplit_cb<<<(K_CODES * C_DIM / 4) / 256, 256, 0, stream>>>(cb, Bsp);
        ksplit_x<<<2048, 256, 0, stream>>>(x, Asp);
        kargmin_mfma<<<16384, 256, 0, stream>>>(Asp, Bsp, cnorm, wsmin);
        kcombine<<<N_ROWS / 256, 256, 0, stream>>>(wsmin, idxf, rcnt, rrows);
        krescue<<<128, 256, 0, stream>>>(x, cb, cnorm, rcnt, rrows, idxf);
        kquant<<<32768, 256, 0, stream>>>(x, cb, idxf, qout, nw, ncnt, loss_arr);
        kstats<<<1, 256, 0, stream>>>(ncnt, loss_arr, out);
        kfinal<<<K_CODES, C_DIM, 0, stream>>>(ema_c, ema_w, ncnt, nw, ncb);
    } else {
        float* cnorm = (float*)d_ws;
        float* loss_arr = cnorm + K_CODES;
        hipMemsetAsync(loss_arr, 0, 256 * sizeof(float), stream);
        knorm<<<K_CODES / 4, 256, 0, stream>>>(cb, cnorm);
        kargmin_fp32<<<N_ROWS / 64, 256, 0, stream>>>(x, cb, cnorm, idxf);
        kquant<<<32768, 256, 0, stream>>>(x, cb, idxf, qout, nw, ncnt, loss_arr);
        kstats<<<1, 256, 0, stream>>>(ncnt, loss_arr, out);
        kfinal<<<K_CODES, C_DIM, 0, stream>>>(ema_c, ema_w, ncnt, nw, ncb);
    }
}

// Round 4
// 2342.740 us; speedup vs baseline: 1.6604x; 1.2040x over previous
//
#include <hip/hip_runtime.h>
#include <hip/hip_bf16.h>
#include <stdint.h>

#define N_ROWS 32768
#define K_CODES 8192
#define C_DIM 256
#define DECAYF 0.95f
#define COMMITF 0.25f
#define EPSF 1e-5f
#define RESC_EPS 0.02f
#define RESC_CAP 4096

// d_out layout (floats), reference return order
#define OFF_QUANT 0
#define OFF_ELOSS 8388608
#define OFF_PERP  8388609
#define OFF_UNIQ  8388610
#define OFF_NCB   8388611
#define OFF_NCNT  10485763
#define OFF_NW    10493955
#define OFF_IDX   12591107

typedef __hip_bfloat16 bf16;
typedef float f32x4 __attribute__((ext_vector_type(4)));
typedef short bf16x8 __attribute__((ext_vector_type(8)));
typedef unsigned long long u64;

#define SWZ(r) ((((r) >> 2) & 7) << 2)

#if defined(__has_builtin)
#if __has_builtin(__builtin_amdgcn_global_load_lds)
#define HAVE_GLDS 1
#endif
#endif
#ifdef HAVE_GLDS
#define GLDS16(g, l) __builtin_amdgcn_global_load_lds( \
    (const __attribute__((address_space(1))) void*)(uintptr_t)(g), \
    (__attribute__((address_space(3))) void*)(uint32_t)(uintptr_t)(l), 16, 0, 0)
#else
#define GLDS16(g, l) do { *(float4*)(l) = *(const float4*)(g); } while (0)
#endif

__device__ __forceinline__ uint32_t fkey(float f) {
    uint32_t b = __float_as_uint(f);
    return b ^ ((uint32_t)((int32_t)b >> 31) | 0x80000000u);
}
__device__ __forceinline__ float funkey(uint32_t k) {
    uint32_t b = (k & 0x80000000u) ? (k ^ 0x80000000u) : ~k;
    return __uint_as_float(b);
}
__device__ __forceinline__ void split2(float v, unsigned short& h, unsigned short& m) {
    bf16 hb = __float2bfloat16(v);
    float fh = __bfloat162float(hb);
    bf16 mb = __float2bfloat16(v - fh);
    h = *(unsigned short*)&hb; m = *(unsigned short*)&mb;
}

// ---------------- codebook row squared-norms ----------------
__global__ void knorm(const float* __restrict__ cb, float* __restrict__ cnorm) {
    const int wid  = threadIdx.x >> 6;
    const int lane = threadIdx.x & 63;
    const int row  = blockIdx.x * 4 + wid;
    const float4 v = *(const float4*)(cb + (size_t)row * C_DIM + lane * 4);
    float s = v.x * v.x + v.y * v.y + v.z * v.z + v.w * v.w;
    #pragma unroll
    for (int off = 32; off; off >>= 1) s += __shfl_down(s, off);
    if (lane == 0) cnorm[row] = s;
}

// ---------------- split codebook into 2 bf16 planes ----------------
__global__ void ksplit_cb(const float* __restrict__ cb, unsigned short* __restrict__ Bsp) {
    const size_t plane = (size_t)K_CODES * C_DIM;
    const size_t i4 = ((size_t)blockIdx.x * 256 + threadIdx.x) * 4;
    const float4 v = *(const float4*)(cb + i4);
    ushort4 h, m;
    split2(v.x, h.x, m.x); split2(v.y, h.y, m.y);
    split2(v.z, h.z, m.z); split2(v.w, h.w, m.w);
    *(ushort4*)(Bsp + i4) = h;
    *(ushort4*)(Bsp + plane + i4) = m;
}

// ---------------- transpose x to [n][c] and split into 2 bf16 planes ----------------
__global__ __launch_bounds__(256)
void ksplit_x(const float* __restrict__ x, unsigned short* __restrict__ Asp) {
    __shared__ float xt[64][65];
    const int t = threadIdx.x;
    const int bid = blockIdx.x;        // 8 b * 4 ct * 64 st = 2048
    const int st = bid & 63;
    const int ct = (bid >> 6) & 3;
    const int b  = bid >> 8;
    const float* xb = x + ((size_t)b * C_DIM + ct * 64) * 4096 + st * 64;
    {
        const int s_l = t & 63, c0 = t >> 6;
        #pragma unroll
        for (int cc = 0; cc < 16; ++cc) {
            int c_l = cc * 4 + c0;
            xt[c_l][s_l] = xb[(size_t)c_l * 4096 + s_l];
        }
    }
    __syncthreads();
    const size_t plane = (size_t)N_ROWS * C_DIM;
    const int c2 = (t & 31) * 2;
    const int s0 = t >> 5;
    #pragma unroll
    for (int ww = 0; ww < 8; ++ww) {
        int s_o = ww * 8 + s0;
        float v0 = xt[c2][s_o], v1 = xt[c2 + 1][s_o];
        unsigned short h0, m0_, h1, m1_;
        split2(v0, h0, m0_); split2(v1, h1, m1_);
        size_t off = ((size_t)(b * 4096 + st * 64 + s_o)) * C_DIM + ct * 64 + c2;
        *(ushort2*)(Asp + off)         = make_ushort2(h0, h1);
        *(ushort2*)(Asp + plane + off) = make_ushort2(m0_, m1_);
    }
}

// ---------------- MFMA distance GEMM + per-row top-2 argmin ----------------
// 3 K-segments (hh, hm, mh); mm dropped (<=~2e-3 distance error, rescue covers).
// 2-phase double-buffered LDS: stage(kt+1) issued BEFORE compute(kt); one
// vmcnt-drain+barrier per K-step (the __syncthreads at loop end).
__global__ __launch_bounds__(256)
void kargmin_mfma(const unsigned short* __restrict__ Asp, const unsigned short* __restrict__ Bsp,
                  const float* __restrict__ cnorm, u64* __restrict__ wsmin) {
    __shared__ unsigned short As[2][128 * 64];
    __shared__ unsigned short Bs[2][128 * 64];

    const int t = threadIdx.x;
    const int lane = t & 63;
    const int wid = t >> 6;
    // bijective chunked XCD swizzle: each XCD gets a contiguous 2048-block
    // range -> one ntile's B-tile stays L2-hot across its mtile sweep
    const int swz = (blockIdx.x & 7) * 2048 + (blockIdx.x >> 3);
    const int mtile = swz & 255;
    const int ntile = swz >> 8;
    const int m0 = mtile * 128;
    const int n0 = ntile * 128;
    const int wm = (wid >> 1) * 64;
    const int wn = (wid & 1) * 64;
    const int lm = lane & 15;
    const int lh = lane >> 4;
    const int l7 = lane & 7;
    const int sr = t >> 3;          // staging row-within-32 group
    const int NKT = 12;             // 3 segments * 4 k-chunks of 64

    f32x4 acc[4][4];
    #pragma unroll
    for (int i = 0; i < 4; ++i)
        #pragma unroll
        for (int j = 0; j < 4; ++j) acc[i][j] = (f32x4){0.f, 0.f, 0.f, 0.f};

    const int PA[3] = {0, 0, 1};
    const int PB[3] = {0, 1, 0};

    // ---- staging: linear LDS dest, inverse-swizzled global source (rule #21)
    auto stage = [&](int kt, int buf) {
        const int seg = kt >> 2;
        const int kk0 = (kt & 3) * 64;
        const unsigned short* Ab = Asp + ((size_t)PA[seg] * N_ROWS + m0) * C_DIM + kk0;
        const unsigned short* Bb = Bsp + ((size_t)PB[seg] * K_CODES + n0) * C_DIM + kk0;
        #pragma unroll
        for (int it = 0; it < 4; ++it) {
            const int chunk = it * 256 + t;
            const int r = it * 32 + sr;
            const int gslot = (t & 7) ^ (r & 7);
            GLDS16(Ab + (size_t)r * C_DIM + gslot * 8, &As[buf][chunk * 8]);
            GLDS16(Bb + (size_t)r * C_DIM + gslot * 8, &Bs[buf][chunk * 8]);
        }
    };

    stage(0, 0);
    __syncthreads();   // drains vmcnt(0): buffer 0 ready

    for (int kt = 0; kt < NKT; ++kt) {
        const int cur = kt & 1;
        if (kt + 1 < NKT) stage(kt + 1, cur ^ 1);   // issue-early: flies under compute
        #pragma unroll
        for (int kh = 0; kh < 2; ++kh) {
            const int sw = (((kh * 4 + lh) ^ l7)) * 8;   // swizzled 8-short slot offset
            bf16x8 a[4], b[4];
            #pragma unroll
            for (int i = 0; i < 4; ++i)
                a[i] = *(const bf16x8*)&As[cur][(wm + i * 16 + lm) * 64 + sw];
            #pragma unroll
            for (int j = 0; j < 4; ++j)
                b[j] = *(const bf16x8*)&Bs[cur][(wn + j * 16 + lm) * 64 + sw];
            #pragma unroll
            for (int i = 0; i < 4; ++i)
                #pragma unroll
                for (int j = 0; j < 4; ++j)
                    acc[i][j] = __builtin_amdgcn_mfma_f32_16x16x32_bf16(a[i], b[j], acc[i][j], 0, 0, 0);
        }
        __syncthreads();   // one drain (vmcnt0+lgkm0) + barrier per K-step
    }

    // epilogue: dist = cnorm - 2*dot ; per-row top-2 packed (distkey<<32 | code)
    float cn[4];
    #pragma unroll
    for (int j = 0; j < 4; ++j) cn[j] = cnorm[n0 + wn + j * 16 + lm];

    u64 p1[4][4], p2[4][4];
    #pragma unroll
    for (int i = 0; i < 4; ++i)
        #pragma unroll
        for (int r = 0; r < 4; ++r) {
            u64 b1 = ~0ull, b2 = ~0ull;
            #pragma unroll
            for (int j = 0; j < 4; ++j) {
                float dist = fmaf(-2.f, acc[i][j][r], cn[j]);
                u64 pk = ((u64)fkey(dist) << 32) | (unsigned)(n0 + wn + j * 16 + lm);
                if (pk < b1) { b2 = b1; b1 = pk; }
                else if (pk < b2) b2 = pk;
            }
            p1[i][r] = b1; p2[i][r] = b2;
        }

    #pragma unroll
    for (int off = 1; off < 16; off <<= 1) {
        #pragma unroll
        for (int i = 0; i < 4; ++i)
            #pragma unroll
            for (int r = 0; r < 4; ++r) {
                u64 o1 = __shfl_xor(p1[i][r], off);
                u64 o2 = __shfl_xor(p2[i][r], off);
                u64 lo = p1[i][r] < o1 ? p1[i][r] : o1;
                u64 hi = p1[i][r] < o1 ? o1 : p1[i][r];
                u64 mn2 = p2[i][r] < o2 ? p2[i][r] : o2;
                p1[i][r] = lo;
                p2[i][r] = hi < mn2 ? hi : mn2;
            }
    }

    u64* redbuf = (u64*)&As[0][0];   // reuse A tile LDS (MFMA reads done)
    __syncthreads();
    if (lm == 0) {
        #pragma unroll
        for (int i = 0; i < 4; ++i)
            #pragma unroll
            for (int r = 0; r < 4; ++r) {
                int rl = wm + i * 16 + lh * 4 + r;
                redbuf[rl * 4 + (wid & 1) * 2 + 0] = p1[i][r];
                redbuf[rl * 4 + (wid & 1) * 2 + 1] = p2[i][r];
            }
    }
    __syncthreads();
    if (t < 128) {
        u64 a1 = redbuf[t * 4 + 0], a2 = redbuf[t * 4 + 1];
        u64 b1 = redbuf[t * 4 + 2], b2 = redbuf[t * 4 + 3];
        u64 lo = a1 < b1 ? a1 : b1;
        u64 hi = a1 < b1 ? b1 : a1;
        u64 mn2 = a2 < b2 ? a2 : b2;
        u64 q2 = hi < mn2 ? hi : mn2;
        size_t o = ((size_t)(m0 + t) * 64 + ntile) * 2;
        wsmin[o] = lo; wsmin[o + 1] = q2;
    }
}

// ---------------- combine per-ntile mins; flag near-ties ----------------
__global__ void kcombine(const u64* __restrict__ wsmin, float* __restrict__ idxf,
                         unsigned* __restrict__ rcnt, unsigned* __restrict__ rrows) {
    const int row = blockIdx.x * 256 + threadIdx.x;
    const u64* p = wsmin + (size_t)row * 128;
    u64 m1 = ~0ull, m2 = ~0ull;
    for (int i = 0; i < 128; i += 2) {
        u64 a = p[i], b = p[i + 1];
        u64 lo = a < m1 ? a : m1;
        u64 hi = a < m1 ? m1 : a;
        u64 c = m2 < b ? m2 : b;
        m1 = lo;
        m2 = hi < c ? hi : c;
    }
    idxf[row] = (float)(unsigned)(m1 & 0xffffffffu);
    float d1 = funkey((uint32_t)(m1 >> 32));
    float d2 = funkey((uint32_t)(m2 >> 32));
    if (d2 - d1 < RESC_EPS) {
        unsigned slot = atomicAdd(rcnt, 1u);
        if (slot < RESC_CAP) rrows[slot] = (unsigned)row;
    }
}

// ---------------- exact fp32 re-score for near-tie rows ----------------
__global__ __launch_bounds__(256)
void krescue(const float* __restrict__ x, const float* __restrict__ cb,
             const float* __restrict__ cnorm, const unsigned* __restrict__ rcnt,
             const unsigned* __restrict__ rrows, float* __restrict__ idxf) {
    __shared__ float xs[256];
    __shared__ u64 red[4];
    unsigned cnt = *rcnt; if (cnt > RESC_CAP) cnt = RESC_CAP;
    for (unsigned li = blockIdx.x; li < cnt; li += gridDim.x) {
        const int row = (int)rrows[li];
        const int b = row >> 12, s = row & 4095;
        xs[threadIdx.x] = x[((size_t)b * C_DIM + threadIdx.x) * 4096 + s];
        __syncthreads();
        u64 best = ~0ull;
        for (int k0 = 0; k0 < K_CODES; k0 += 256) {
            const int k = k0 + threadIdx.x;
            const float* cr = cb + (size_t)k * C_DIM;
            float dot = 0.f;
            #pragma unroll 8
            for (int c = 0; c < C_DIM; ++c) dot = fmaf(xs[c], cr[c], dot);
            float dist = fmaf(-2.f, dot, cnorm[k]);
            u64 pk = ((u64)fkey(dist) << 32) | (unsigned)k;
            if (pk < best) best = pk;
        }
        #pragma unroll
        for (int off = 32; off; off >>= 1) {
            u64 o = __shfl_down(best, off);
            if (o < best) best = o;
        }
        if ((threadIdx.x & 63) == 0) red[threadIdx.x >> 6] = best;
        __syncthreads();
        if (threadIdx.x == 0) {
            u64 r0 = red[0];
            #pragma unroll
            for (int w = 1; w < 4; ++w) if (red[w] < r0) r0 = red[w];
            idxf[row] = (float)(unsigned)(r0 & 0xffffffffu);
        }
        __syncthreads();
    }
}

// ---------------- fallback fp32 argmin (round-1 kernel) ----------------
__launch_bounds__(256, 1)
__global__ void kargmin_fp32(const float* __restrict__ x, const float* __restrict__ cb,
                             const float* __restrict__ cnorm, float* __restrict__ idxf) {
    __shared__ float xs[64][256];
    __shared__ float es[64][256];
    const int t  = threadIdx.x;
    const int n0 = blockIdx.x * 64;
    const int b  = n0 >> 12;
    const int s0 = n0 & 4095;
    {
        const int r  = t & 63;
        const int c0 = t >> 6;
        const float* xb = x + (size_t)b * C_DIM * 4096 + s0 + r;
        const int sw = SWZ(r);
        #pragma unroll 8
        for (int cc = 0; cc < 64; ++cc) {
            int c = cc * 4 + c0;
            xs[r][c ^ sw] = xb[(size_t)c * 4096];
        }
    }
    const int mg  = t >> 4;
    const int ng  = t & 15;
    const int m0  = mg * 4;
    const int nn0 = ng * 4;
    const int swm = SWZ(m0);
    const int swn = SWZ(nn0);
    float minv[4] = {1e30f, 1e30f, 1e30f, 1e30f};
    int   mini[4] = {0, 0, 0, 0};
    for (int k0 = 0; k0 < K_CODES; k0 += 64) {
        __syncthreads();
        {
            const int lane = t & 63;
            const int cw   = t >> 6;
            #pragma unroll
            for (int p = 0; p < 16; ++p) {
                int code = p * 4 + cw;
                float4 v = *(const float4*)(cb + (size_t)(k0 + code) * C_DIM + lane * 4);
                *(float4*)&es[code][(lane * 4) ^ SWZ(code)] = v;
            }
        }
        float cn[4];
        #pragma unroll
        for (int j = 0; j < 4; ++j) cn[j] = cnorm[k0 + nn0 + j];
        __syncthreads();
        float acc[4][4];
        #pragma unroll
        for (int i = 0; i < 4; ++i)
            #pragma unroll
            for (int j = 0; j < 4; ++j) acc[i][j] = 0.f;
        #pragma unroll 4
        for (int c = 0; c < C_DIM; c += 4) {
            float4 xa[4], eb[4];
            #pragma unroll
            for (int i = 0; i < 4; ++i) xa[i] = *(const float4*)&xs[m0 + i][c ^ swm];
            #pragma unroll
            for (int j = 0; j < 4; ++j) eb[j] = *(const float4*)&es[nn0 + j][c ^ swn];
            #pragma unroll
            for (int i = 0; i < 4; ++i)
                #pragma unroll
                for (int j = 0; j < 4; ++j)
                    acc[i][j] += xa[i].x * eb[j].x + xa[i].y * eb[j].y +
                                 xa[i].z * eb[j].z + xa[i].w * eb[j].w;
        }
        #pragma unroll
        for (int j = 0; j < 4; ++j) {
            const int kg = k0 + nn0 + j;
            #pragma unroll
            for (int i = 0; i < 4; ++i) {
                float dist = fmaf(-2.f, acc[i][j], cn[j]);
                if (dist < minv[i]) { minv[i] = dist; mini[i] = kg; }
            }
        }
    }
    #pragma unroll
    for (int off = 1; off < 16; off <<= 1) {
        #pragma unroll
        for (int i = 0; i < 4; ++i) {
            float ov = __shfl_xor(minv[i], off);
            int   oi = __shfl_xor(mini[i], off);
            if (ov < minv[i] || (ov == minv[i] && oi < mini[i])) { minv[i] = ov; mini[i] = oi; }
        }
    }
    if (ng == 0) {
        #pragma unroll
        for (int i = 0; i < 4; ++i) idxf[n0 + m0 + i] = (float)mini[i];
    }
}

// ---------------- quantize + e_loss partials + segment sums ----------------
__global__ void kquant(const float* __restrict__ x, const float* __restrict__ cb,
                       const float* __restrict__ idxf, float* __restrict__ qout,
                       float* __restrict__ dw, float* __restrict__ counts,
                       float* __restrict__ loss_arr) {
    const int t   = threadIdx.x;
    const int bid = blockIdx.x;
    const int sc  = bid & 15;
    const int c   = (bid >> 4) & 255;
    const int b   = bid >> 12;
    const int s   = sc * 256 + t;
    const int n   = b * 4096 + s;
    const int k   = (int)idxf[n];

    const size_t xoff = ((size_t)b * C_DIM + c) * 4096 + s;
    const float xv = x[xoff];
    const float q  = cb[(size_t)k * C_DIM + c];
    qout[xoff] = xv + (q - xv);
    atomicAdd(&dw[(size_t)k * C_DIM + c], xv);
    if (c == 0) atomicAdd(&counts[k], 1.0f);

    float d = q - xv;
    float p = d * d;
    #pragma unroll
    for (int off = 32; off; off >>= 1) p += __shfl_down(p, off);
    __shared__ float ps[4];
    if ((t & 63) == 0) ps[t >> 6] = p;
    __syncthreads();
    if (t == 0) atomicAdd(&loss_arr[bid & 255], ps[0] + ps[1] + ps[2] + ps[3]);
}

// ---------------- perplexity / unique / e_loss ----------------
__global__ void kstats(const float* __restrict__ counts, const float* __restrict__ loss_arr,
                       float* __restrict__ out) {
    const int t = threadIdx.x;
    float nz = 0.f, s = 0.f;
    for (int k = t; k < K_CODES; k += 256) {
        float cnt = counts[k];
        if (cnt != 0.f) nz += 1.f;
        float p = cnt * (1.f / 32768.f);
        s += p * logf(p + 1e-10f);
    }
    float ls = loss_arr[t];
    #pragma unroll
    for (int off = 32; off; off >>= 1) {
        s  += __shfl_down(s, off);
        nz += __shfl_down(nz, off);
        ls += __shfl_down(ls, off);
    }
    __shared__ float ss[4], zz[4], ll[4];
    const int wid = t >> 6, lane = t & 63;
    if (lane == 0) { ss[wid] = s; zz[wid] = nz; ll[wid] = ls; }
    __syncthreads();
    if (t == 0) {
        float st = ss[0] + ss[1] + ss[2] + ss[3];
        float zt = zz[0] + zz[1] + zz[2] + zz[3];
        float lt = ll[0] + ll[1] + ll[2] + ll[3];
        out[OFF_ELOSS] = COMMITF * lt / 8388608.f;
        out[OFF_PERP]  = expf(-st);
        out[OFF_UNIQ]  = zt;
    }
}

// ---------------- EMA finalize ----------------
__global__ void kfinal(const float* __restrict__ ema_c, const float* __restrict__ ema_w,
                       float* __restrict__ counts, float* __restrict__ dw,
                       float* __restrict__ ncb) {
    const int k = blockIdx.x;
    const int c = threadIdx.x;
    const float cnt  = counts[k];
    const float ncnt = (DECAYF * ema_c[k] + (1.f - DECAYF) * cnt + EPSF)
                       / (8.f + (float)K_CODES * EPSF) * 8.f;
    const size_t o = (size_t)k * C_DIM + c;
    const float nw = DECAYF * ema_w[o] + (1.f - DECAYF) * dw[o];
    __syncthreads();
    dw[o]  = nw;
    ncb[o] = nw / ncnt;
    if (c == 0) counts[k] = ncnt;
}

extern "C" void kernel_launch(void* const* d_in, const int* in_sizes, int n_in,
                              void* d_out, int out_size, void* d_ws, size_t ws_size,
                              hipStream_t stream) {
    const float* x     = (const float*)d_in[0];
    const float* cb    = (const float*)d_in[1];
    const float* ema_c = (const float*)d_in[2];
    const float* ema_w = (const float*)d_in[3];
    float* out = (float*)d_out;

    float* qout = out + OFF_QUANT;
    float* ncb  = out + OFF_NCB;
    float* ncnt = out + OFF_NCNT;
    float* nw   = out + OFF_NW;
    float* idxf = out + OFF_IDX;

    const size_t planeA = (size_t)2 * N_ROWS * C_DIM;   // bf16 elems (h,m)
    const size_t planeB = (size_t)2 * K_CODES * C_DIM;
    const size_t need = (planeA + planeB) * 2 + (size_t)K_CODES * 4 + 256 * 4 + 4 + RESC_CAP * 4;
    const bool use_mfma = ws_size >= need;

    hipMemsetAsync(ncnt, 0, K_CODES * sizeof(float), stream);
    hipMemsetAsync(nw, 0, (size_t)K_CODES * C_DIM * sizeof(float), stream);

    if (use_mfma) {
        unsigned short* Asp = (unsigned short*)d_ws;
        unsigned short* Bsp = Asp + planeA;
        float* cnorm = (float*)(Bsp + planeB);
        float* loss_arr = cnorm + K_CODES;
        unsigned* rcnt = (unsigned*)(loss_arr + 256);
        unsigned* rrows = rcnt + 1;
        u64* wsmin = (u64*)(out + OFF_QUANT);   // 33.5 MB, consumed before kquant writes qout

        hipMemsetAsync(loss_arr, 0, 256 * sizeof(float), stream);
        hipMemsetAsync(rcnt, 0, sizeof(unsigned), stream);

        knorm<<<K_CODES / 4, 256, 0, stream>>>(cb, cnorm);
        ksplit_cb<<<(K_CODES * C_DIM / 4) / 256, 256, 0, stream>>>(cb, Bsp);
        ksplit_x<<<2048, 256, 0, stream>>>(x, Asp);
        kargmin_mfma<<<16384, 256, 0, stream>>>(Asp, Bsp, cnorm, wsmin);
        kcombine<<<N_ROWS / 256, 256, 0, stream>>>(wsmin, idxf, rcnt, rrows);
        krescue<<<128, 256, 0, stream>>>(x, cb, cnorm, rcnt, rrows, idxf);
        kquant<<<32768, 256, 0, stream>>>(x, cb, idxf, qout, nw, ncnt, loss_arr);
        kstats<<<1, 256, 0, stream>>>(ncnt, loss_arr, out);
        kfinal<<<K_CODES, C_DIM, 0, stream>>>(ema_c, ema_w, ncnt, nw, ncb);
    } else {
        float* cnorm = (float*)d_ws;
        float* loss_arr = cnorm + K_CODES;
        hipMemsetAsync(loss_arr, 0, 256 * sizeof(float), stream);
        knorm<<<K_CODES / 4, 256, 0, stream>>>(cb, cnorm);
        kargmin_fp32<<<N_ROWS / 64, 256, 0, stream>>>(x, cb, cnorm, idxf);
        kquant<<<32768, 256, 0, stream>>>(x, cb, idxf, qout, nw, ncnt, loss_arr);
        kstats<<<1, 256, 0, stream>>>(ncnt, loss_arr, out);
        kfinal<<<K_CODES, C_DIM, 0, stream>>>(ema_c, ema_w, ncnt, nw, ncb);
    }
}

// Round 5
// 1783.636 us; speedup vs baseline: 2.1809x; 1.3135x over previous
//
#include <hip/hip_runtime.h>
#include <hip/hip_bf16.h>
#include <stdint.h>

#define N_ROWS 32768
#define K_CODES 8192
#define C_DIM 256
#define DECAYF 0.95f
#define COMMITF 0.25f
#define EPSF 1e-5f
#define RESC_EPS 0.02f
#define RESC_CAP 4096

// d_out layout (floats), reference return order
#define OFF_QUANT 0
#define OFF_ELOSS 8388608
#define OFF_PERP  8388609
#define OFF_UNIQ  8388610
#define OFF_NCB   8388611
#define OFF_NCNT  10485763
#define OFF_NW    10493955
#define OFF_IDX   12591107

typedef __hip_bfloat16 bf16;
typedef float f32x4 __attribute__((ext_vector_type(4)));
typedef short bf16x8 __attribute__((ext_vector_type(8)));
typedef unsigned long long u64;

#define SWZ(r) ((((r) >> 2) & 7) << 2)

#if defined(__has_builtin)
#if __has_builtin(__builtin_amdgcn_global_load_lds)
#define HAVE_GLDS 1
#endif
#endif
#ifdef HAVE_GLDS
#define GLDS16(g, l) __builtin_amdgcn_global_load_lds( \
    (const __attribute__((address_space(1))) void*)(uintptr_t)(g), \
    (__attribute__((address_space(3))) void*)(uint32_t)(uintptr_t)(l), 16, 0, 0)
#else
#define GLDS16(g, l) do { *(float4*)(l) = *(const float4*)(g); } while (0)
#endif

__device__ __forceinline__ uint32_t fkey(float f) {
    uint32_t b = __float_as_uint(f);
    return b ^ ((uint32_t)((int32_t)b >> 31) | 0x80000000u);
}
__device__ __forceinline__ float funkey(uint32_t k) {
    uint32_t b = (k & 0x80000000u) ? (k ^ 0x80000000u) : ~k;
    return __uint_as_float(b);
}
__device__ __forceinline__ void split2(float v, unsigned short& h, unsigned short& m) {
    bf16 hb = __float2bfloat16(v);
    float fh = __bfloat162float(hb);
    bf16 mb = __float2bfloat16(v - fh);
    h = *(unsigned short*)&hb; m = *(unsigned short*)&mb;
}

// ---------------- codebook row squared-norms ----------------
__global__ void knorm(const float* __restrict__ cb, float* __restrict__ cnorm) {
    const int wid  = threadIdx.x >> 6;
    const int lane = threadIdx.x & 63;
    const int row  = blockIdx.x * 4 + wid;
    const float4 v = *(const float4*)(cb + (size_t)row * C_DIM + lane * 4);
    float s = v.x * v.x + v.y * v.y + v.z * v.z + v.w * v.w;
    #pragma unroll
    for (int off = 32; off; off >>= 1) s += __shfl_down(s, off);
    if (lane == 0) cnorm[row] = s;
}

// ---------------- split codebook into 2 bf16 planes ----------------
__global__ void ksplit_cb(const float* __restrict__ cb, unsigned short* __restrict__ Bsp) {
    const size_t plane = (size_t)K_CODES * C_DIM;
    const size_t i4 = ((size_t)blockIdx.x * 256 + threadIdx.x) * 4;
    const float4 v = *(const float4*)(cb + i4);
    ushort4 h, m;
    split2(v.x, h.x, m.x); split2(v.y, h.y, m.y);
    split2(v.z, h.z, m.z); split2(v.w, h.w, m.w);
    *(ushort4*)(Bsp + i4) = h;
    *(ushort4*)(Bsp + plane + i4) = m;
}

// ---------------- transpose x to [n][c] and split into 2 bf16 planes ----------------
__global__ __launch_bounds__(256)
void ksplit_x(const float* __restrict__ x, unsigned short* __restrict__ Asp) {
    __shared__ float xt[64][65];
    const int t = threadIdx.x;
    const int bid = blockIdx.x;        // 8 b * 4 ct * 64 st = 2048
    const int st = bid & 63;
    const int ct = (bid >> 6) & 3;
    const int b  = bid >> 8;
    const float* xb = x + ((size_t)b * C_DIM + ct * 64) * 4096 + st * 64;
    {
        const int s_l = t & 63, c0 = t >> 6;
        #pragma unroll
        for (int cc = 0; cc < 16; ++cc) {
            int c_l = cc * 4 + c0;
            xt[c_l][s_l] = xb[(size_t)c_l * 4096 + s_l];
        }
    }
    __syncthreads();
    const size_t plane = (size_t)N_ROWS * C_DIM;
    const int c2 = (t & 31) * 2;
    const int s0 = t >> 5;
    #pragma unroll
    for (int ww = 0; ww < 8; ++ww) {
        int s_o = ww * 8 + s0;
        float v0 = xt[c2][s_o], v1 = xt[c2 + 1][s_o];
        unsigned short h0, m0_, h1, m1_;
        split2(v0, h0, m0_); split2(v1, h1, m1_);
        size_t off = ((size_t)(b * 4096 + st * 64 + s_o)) * C_DIM + ct * 64 + c2;
        *(ushort2*)(Asp + off)         = make_ushort2(h0, h1);
        *(ushort2*)(Asp + plane + off) = make_ushort2(m0_, m1_);
    }
}

// ---------------- MFMA distance GEMM + per-row top-2 argmin ----------------
// 256x256 block tile, 512 threads = 8 waves (2M x 4N), per-wave 128x64 out
// (8x4 acc of 16x16x32). 3 K-segments (hh,hm,mh). 2-phase double-buffered
// 128 KiB LDS, issue-early staging, swizzled tiles (rule #21 both-sides).
__global__ __launch_bounds__(512, 2)
void kargmin_mfma(const unsigned short* __restrict__ Asp, const unsigned short* __restrict__ Bsp,
                  const float* __restrict__ cnorm, u64* __restrict__ wsmin) {
    __shared__ unsigned short As[2][256 * 64];   // 32KB x2
    __shared__ unsigned short Bs[2][256 * 64];   // 32KB x2

    const int t = threadIdx.x;
    const int lane = t & 63;
    const int wid = t >> 6;                    // 0..7
    // bijective chunked XCD swizzle (4096 % 8 == 0): 512 blocks per XCD
    // = 4 ntiles x 128 mtiles -> B panel stays L2-hot per XCD
    const int swz = (blockIdx.x & 7) * 512 + (blockIdx.x >> 3);
    const int mtile = swz & 127;
    const int ntile = swz >> 7;                // 0..31
    const int m0 = mtile * 256;
    const int n0 = ntile * 256;
    const int wr = wid >> 2;                   // 0..1
    const int wc = wid & 3;                    // 0..3
    const int wm = wr * 128;
    const int wn = wc * 64;
    const int lm = lane & 15;
    const int lh = lane >> 4;
    const int l7 = lane & 7;
    const int NKT = 12;                        // 3 segments * 4 k-chunks of 64

    f32x4 acc[8][4];
    #pragma unroll
    for (int i = 0; i < 8; ++i)
        #pragma unroll
        for (int j = 0; j < 4; ++j) acc[i][j] = (f32x4){0.f, 0.f, 0.f, 0.f};

    const int PA[3] = {0, 0, 1};
    const int PB[3] = {0, 1, 0};

    // staging constants: 2048 chunks of 16B per tile, 4 rounds of 512 threads
    const int sgr = t >> 3;                     // 0..63
    const int gslot = (t & 7) ^ (sgr & 7);      // inverse-swizzled source slot

    auto stage = [&](int kt, int buf) {
        const int seg = kt >> 2;
        const int kk0 = (kt & 3) * 64;
        const unsigned short* Ab = Asp + ((size_t)PA[seg] * N_ROWS + m0) * C_DIM + kk0;
        const unsigned short* Bb = Bsp + ((size_t)PB[seg] * K_CODES + n0) * C_DIM + kk0;
        #pragma unroll
        for (int it = 0; it < 4; ++it) {
            const int chunk = it * 512 + t;
            const int r = it * 64 + sgr;       // r&7 == sgr&7
            GLDS16(Ab + (size_t)r * C_DIM + gslot * 8, &As[buf][chunk * 8]);
            GLDS16(Bb + (size_t)r * C_DIM + gslot * 8, &Bs[buf][chunk * 8]);
        }
    };

    stage(0, 0);
    __syncthreads();   // drain vmcnt(0): buffer 0 ready

    for (int kt = 0; kt < NKT; ++kt) {
        const int cur = kt & 1;
        if (kt + 1 < NKT) stage(kt + 1, cur ^ 1);   // issue-early, flies under compute
        #pragma unroll
        for (int kh = 0; kh < 2; ++kh) {
            const int sw = ((kh * 4 + lh) ^ l7) * 8;   // swizzled 8-short slot
            bf16x8 a[8], b[4];
            #pragma unroll
            for (int j = 0; j < 4; ++j)
                b[j] = *(const bf16x8*)&Bs[cur][(wn + j * 16 + lm) * 64 + sw];
            #pragma unroll
            for (int i = 0; i < 8; ++i)
                a[i] = *(const bf16x8*)&As[cur][(wm + i * 16 + lm) * 64 + sw];
            #pragma unroll
            for (int i = 0; i < 8; ++i)
                #pragma unroll
                for (int j = 0; j < 4; ++j)
                    acc[i][j] = __builtin_amdgcn_mfma_f32_16x16x32_bf16(a[i], b[j], acc[i][j], 0, 0, 0);
        }
        __syncthreads();   // one drain + barrier per K-step
    }

    // epilogue: dist = cnorm - 2*dot ; per-row top-2 (distkey<<32 | code)
    float cn[4];
    #pragma unroll
    for (int j = 0; j < 4; ++j) cn[j] = cnorm[n0 + wn + j * 16 + lm];

    u64* redbuf = (u64*)&As[0][0];   // 256 rows x 4 wc x 2 u64 = 16KB, MFMA reads done
    // all waves are past the final K-loop barrier; process i-slices streaming
    #pragma unroll
    for (int i = 0; i < 8; ++i) {
        u64 p1[4], p2[4];
        #pragma unroll
        for (int r = 0; r < 4; ++r) {
            u64 b1 = ~0ull, b2 = ~0ull;
            #pragma unroll
            for (int j = 0; j < 4; ++j) {
                float dist = fmaf(-2.f, acc[i][j][r], cn[j]);
                u64 pk = ((u64)fkey(dist) << 32) | (unsigned)(n0 + wn + j * 16 + lm);
                if (pk < b1) { b2 = b1; b1 = pk; }
                else if (pk < b2) b2 = pk;
            }
            p1[r] = b1; p2[r] = b2;
        }
        #pragma unroll
        for (int off = 1; off < 16; off <<= 1) {
            #pragma unroll
            for (int r = 0; r < 4; ++r) {
                u64 o1 = __shfl_xor(p1[r], off);
                u64 o2 = __shfl_xor(p2[r], off);
                u64 lo = p1[r] < o1 ? p1[r] : o1;
                u64 hi = p1[r] < o1 ? o1 : p1[r];
                u64 mn2 = p2[r] < o2 ? p2[r] : o2;
                p1[r] = lo;
                p2[r] = hi < mn2 ? hi : mn2;
            }
        }
        if (lm == 0) {
            #pragma unroll
            for (int r = 0; r < 4; ++r) {
                const int rl = wm + i * 16 + lh * 4 + r;   // 0..255
                redbuf[rl * 8 + wc * 2 + 0] = p1[r];
                redbuf[rl * 8 + wc * 2 + 1] = p2[r];
            }
        }
    }
    __syncthreads();
    if (t < 256) {
        u64 m1 = ~0ull, m2 = ~0ull;
        #pragma unroll
        for (int w = 0; w < 4; ++w) {
            u64 a1 = redbuf[t * 8 + w * 2 + 0];
            u64 a2 = redbuf[t * 8 + w * 2 + 1];
            u64 lo = m1 < a1 ? m1 : a1;
            u64 hi = m1 < a1 ? a1 : m1;
            u64 mn2 = m2 < a2 ? m2 : a2;
            m1 = lo;
            m2 = hi < mn2 ? hi : mn2;
        }
        size_t o = ((size_t)(m0 + t) * 32 + ntile) * 2;
        wsmin[o] = m1; wsmin[o + 1] = m2;
    }
}

// ---------------- combine per-ntile mins; flag near-ties ----------------
__global__ void kcombine(const u64* __restrict__ wsmin, float* __restrict__ idxf,
                         unsigned* __restrict__ rcnt, unsigned* __restrict__ rrows) {
    const int row = blockIdx.x * 256 + threadIdx.x;
    const u64* p = wsmin + (size_t)row * 64;
    u64 m1 = ~0ull, m2 = ~0ull;
    for (int i = 0; i < 64; i += 2) {
        u64 a = p[i], b = p[i + 1];
        u64 lo = a < m1 ? a : m1;
        u64 hi = a < m1 ? m1 : a;
        u64 c = m2 < b ? m2 : b;
        m1 = lo;
        m2 = hi < c ? hi : c;
    }
    idxf[row] = (float)(unsigned)(m1 & 0xffffffffu);
    float d1 = funkey((uint32_t)(m1 >> 32));
    float d2 = funkey((uint32_t)(m2 >> 32));
    if (d2 - d1 < RESC_EPS) {
        unsigned slot = atomicAdd(rcnt, 1u);
        if (slot < RESC_CAP) rrows[slot] = (unsigned)row;
    }
}

// ---------------- exact fp32 re-score for near-tie rows ----------------
__global__ __launch_bounds__(256)
void krescue(const float* __restrict__ x, const float* __restrict__ cb,
             const float* __restrict__ cnorm, const unsigned* __restrict__ rcnt,
             const unsigned* __restrict__ rrows, float* __restrict__ idxf) {
    __shared__ float xs[256];
    __shared__ u64 red[4];
    unsigned cnt = *rcnt; if (cnt > RESC_CAP) cnt = RESC_CAP;
    for (unsigned li = blockIdx.x; li < cnt; li += gridDim.x) {
        const int row = (int)rrows[li];
        const int b = row >> 12, s = row & 4095;
        xs[threadIdx.x] = x[((size_t)b * C_DIM + threadIdx.x) * 4096 + s];
        __syncthreads();
        u64 best = ~0ull;
        for (int k0 = 0; k0 < K_CODES; k0 += 256) {
            const int k = k0 + threadIdx.x;
            const float* cr = cb + (size_t)k * C_DIM;
            float dot = 0.f;
            #pragma unroll 8
            for (int c = 0; c < C_DIM; ++c) dot = fmaf(xs[c], cr[c], dot);
            float dist = fmaf(-2.f, dot, cnorm[k]);
            u64 pk = ((u64)fkey(dist) << 32) | (unsigned)k;
            if (pk < best) best = pk;
        }
        #pragma unroll
        for (int off = 32; off; off >>= 1) {
            u64 o = __shfl_down(best, off);
            if (o < best) best = o;
        }
        if ((threadIdx.x & 63) == 0) red[threadIdx.x >> 6] = best;
        __syncthreads();
        if (threadIdx.x == 0) {
            u64 r0 = red[0];
            #pragma unroll
            for (int w = 1; w < 4; ++w) if (red[w] < r0) r0 = red[w];
            idxf[row] = (float)(unsigned)(r0 & 0xffffffffu);
        }
        __syncthreads();
    }
}

// ---------------- fallback fp32 argmin (round-1 kernel) ----------------
__launch_bounds__(256, 1)
__global__ void kargmin_fp32(const float* __restrict__ x, const float* __restrict__ cb,
                             const float* __restrict__ cnorm, float* __restrict__ idxf) {
    __shared__ float xs[64][256];
    __shared__ float es[64][256];
    const int t  = threadIdx.x;
    const int n0 = blockIdx.x * 64;
    const int b  = n0 >> 12;
    const int s0 = n0 & 4095;
    {
        const int r  = t & 63;
        const int c0 = t >> 6;
        const float* xb = x + (size_t)b * C_DIM * 4096 + s0 + r;
        const int sw = SWZ(r);
        #pragma unroll 8
        for (int cc = 0; cc < 64; ++cc) {
            int c = cc * 4 + c0;
            xs[r][c ^ sw] = xb[(size_t)c * 4096];
        }
    }
    const int mg  = t >> 4;
    const int ng  = t & 15;
    const int m0  = mg * 4;
    const int nn0 = ng * 4;
    const int swm = SWZ(m0);
    const int swn = SWZ(nn0);
    float minv[4] = {1e30f, 1e30f, 1e30f, 1e30f};
    int   mini[4] = {0, 0, 0, 0};
    for (int k0 = 0; k0 < K_CODES; k0 += 64) {
        __syncthreads();
        {
            const int lane = t & 63;
            const int cw   = t >> 6;
            #pragma unroll
            for (int p = 0; p < 16; ++p) {
                int code = p * 4 + cw;
                float4 v = *(const float4*)(cb + (size_t)(k0 + code) * C_DIM + lane * 4);
                *(float4*)&es[code][(lane * 4) ^ SWZ(code)] = v;
            }
        }
        float cn[4];
        #pragma unroll
        for (int j = 0; j < 4; ++j) cn[j] = cnorm[k0 + nn0 + j];
        __syncthreads();
        float acc[4][4];
        #pragma unroll
        for (int i = 0; i < 4; ++i)
            #pragma unroll
            for (int j = 0; j < 4; ++j) acc[i][j] = 0.f;
        #pragma unroll 4
        for (int c = 0; c < C_DIM; c += 4) {
            float4 xa[4], eb[4];
            #pragma unroll
            for (int i = 0; i < 4; ++i) xa[i] = *(const float4*)&xs[m0 + i][c ^ swm];
            #pragma unroll
            for (int j = 0; j < 4; ++j) eb[j] = *(const float4*)&es[nn0 + j][c ^ swn];
            #pragma unroll
            for (int i = 0; i < 4; ++i)
                #pragma unroll
                for (int j = 0; j < 4; ++j)
                    acc[i][j] += xa[i].x * eb[j].x + xa[i].y * eb[j].y +
                                 xa[i].z * eb[j].z + xa[i].w * eb[j].w;
        }
        #pragma unroll
        for (int j = 0; j < 4; ++j) {
            const int kg = k0 + nn0 + j;
            #pragma unroll
            for (int i = 0; i < 4; ++i) {
                float dist = fmaf(-2.f, acc[i][j], cn[j]);
                if (dist < minv[i]) { minv[i] = dist; mini[i] = kg; }
            }
        }
    }
    #pragma unroll
    for (int off = 1; off < 16; off <<= 1) {
        #pragma unroll
        for (int i = 0; i < 4; ++i) {
            float ov = __shfl_xor(minv[i], off);
            int   oi = __shfl_xor(mini[i], off);
            if (ov < minv[i] || (ov == minv[i] && oi < mini[i])) { minv[i] = ov; mini[i] = oi; }
        }
    }
    if (ng == 0) {
        #pragma unroll
        for (int i = 0; i < 4; ++i) idxf[n0 + m0 + i] = (float)mini[i];
    }
}

// ---------------- quantize + e_loss partials + segment sums ----------------
__global__ void kquant(const float* __restrict__ x, const float* __restrict__ cb,
                       const float* __restrict__ idxf, float* __restrict__ qout,
                       float* __restrict__ dw, float* __restrict__ counts,
                       float* __restrict__ loss_arr) {
    const int t   = threadIdx.x;
    const int bid = blockIdx.x;
    const int sc  = bid & 15;
    const int c   = (bid >> 4) & 255;
    const int b   = bid >> 12;
    const int s   = sc * 256 + t;
    const int n   = b * 4096 + s;
    const int k   = (int)idxf[n];

    const size_t xoff = ((size_t)b * C_DIM + c) * 4096 + s;
    const float xv = x[xoff];
    const float q  = cb[(size_t)k * C_DIM + c];
    qout[xoff] = xv + (q - xv);
    atomicAdd(&dw[(size_t)k * C_DIM + c], xv);
    if (c == 0) atomicAdd(&counts[k], 1.0f);

    float d = q - xv;
    float p = d * d;
    #pragma unroll
    for (int off = 32; off; off >>= 1) p += __shfl_down(p, off);
    __shared__ float ps[4];
    if ((t & 63) == 0) ps[t >> 6] = p;
    __syncthreads();
    if (t == 0) atomicAdd(&loss_arr[bid & 255], ps[0] + ps[1] + ps[2] + ps[3]);
}

// ---------------- perplexity / unique / e_loss ----------------
__global__ void kstats(const float* __restrict__ counts, const float* __restrict__ loss_arr,
                       float* __restrict__ out) {
    const int t = threadIdx.x;
    float nz = 0.f, s = 0.f;
    for (int k = t; k < K_CODES; k += 256) {
        float cnt = counts[k];
        if (cnt != 0.f) nz += 1.f;
        float p = cnt * (1.f / 32768.f);
        s += p * logf(p + 1e-10f);
    }
    float ls = loss_arr[t];
    #pragma unroll
    for (int off = 32; off; off >>= 1) {
        s  += __shfl_down(s, off);
        nz += __shfl_down(nz, off);
        ls += __shfl_down(ls, off);
    }
    __shared__ float ss[4], zz[4], ll[4];
    const int wid = t >> 6, lane = t & 63;
    if (lane == 0) { ss[wid] = s; zz[wid] = nz; ll[wid] = ls; }
    __syncthreads();
    if (t == 0) {
        float st = ss[0] + ss[1] + ss[2] + ss[3];
        float zt = zz[0] + zz[1] + zz[2] + zz[3];
        float lt = ll[0] + ll[1] + ll[2] + ll[3];
        out[OFF_ELOSS] = COMMITF * lt / 8388608.f;
        out[OFF_PERP]  = expf(-st);
        out[OFF_UNIQ]  = zt;
    }
}

// ---------------- EMA finalize ----------------
__global__ void kfinal(const float* __restrict__ ema_c, const float* __restrict__ ema_w,
                       float* __restrict__ counts, float* __restrict__ dw,
                       float* __restrict__ ncb) {
    const int k = blockIdx.x;
    const int c = threadIdx.x;
    const float cnt  = counts[k];
    const float ncnt = (DECAYF * ema_c[k] + (1.f - DECAYF) * cnt + EPSF)
                       / (8.f + (float)K_CODES * EPSF) * 8.f;
    const size_t o = (size_t)k * C_DIM + c;
    const float nw = DECAYF * ema_w[o] + (1.f - DECAYF) * dw[o];
    __syncthreads();
    dw[o]  = nw;
    ncb[o] = nw / ncnt;
    if (c == 0) counts[k] = ncnt;
}

extern "C" void kernel_launch(void* const* d_in, const int* in_sizes, int n_in,
                              void* d_out, int out_size, void* d_ws, size_t ws_size,
                              hipStream_t stream) {
    const float* x     = (const float*)d_in[0];
    const float* cb    = (const float*)d_in[1];
    const float* ema_c = (const float*)d_in[2];
    const float* ema_w = (const float*)d_in[3];
    float* out = (float*)d_out;

    float* qout = out + OFF_QUANT;
    float* ncb  = out + OFF_NCB;
    float* ncnt = out + OFF_NCNT;
    float* nw   = out + OFF_NW;
    float* idxf = out + OFF_IDX;

    const size_t planeA = (size_t)2 * N_ROWS * C_DIM;   // bf16 elems (h,m)
    const size_t planeB = (size_t)2 * K_CODES * C_DIM;
    const size_t need = (planeA + planeB) * 2 + (size_t)K_CODES * 4 + 256 * 4 + 4 + RESC_CAP * 4;
    const bool use_mfma = ws_size >= need;

    hipMemsetAsync(ncnt, 0, K_CODES * sizeof(float), stream);
    hipMemsetAsync(nw, 0, (size_t)K_CODES * C_DIM * sizeof(float), stream);

    if (use_mfma) {
        unsigned short* Asp = (unsigned short*)d_ws;
        unsigned short* Bsp = Asp + planeA;
        float* cnorm = (float*)(Bsp + planeB);
        float* loss_arr = cnorm + K_CODES;
        unsigned* rcnt = (unsigned*)(loss_arr + 256);
        unsigned* rrows = rcnt + 1;
        u64* wsmin = (u64*)(out + OFF_QUANT);   // 16 MB, consumed before kquant writes qout

        hipMemsetAsync(loss_arr, 0, 256 * sizeof(float), stream);
        hipMemsetAsync(rcnt, 0, sizeof(unsigned), stream);

        knorm<<<K_CODES / 4, 256, 0, stream>>>(cb, cnorm);
        ksplit_cb<<<(K_CODES * C_DIM / 4) / 256, 256, 0, stream>>>(cb, Bsp);
        ksplit_x<<<2048, 256, 0, stream>>>(x, Asp);
        kargmin_mfma<<<4096, 512, 0, stream>>>(Asp, Bsp, cnorm, wsmin);
        kcombine<<<N_ROWS / 256, 256, 0, stream>>>(wsmin, idxf, rcnt, rrows);
        krescue<<<128, 256, 0, stream>>>(x, cb, cnorm, rcnt, rrows, idxf);
        kquant<<<32768, 256, 0, stream>>>(x, cb, idxf, qout, nw, ncnt, loss_arr);
        kstats<<<1, 256, 0, stream>>>(ncnt, loss_arr, out);
        kfinal<<<K_CODES, C_DIM, 0, stream>>>(ema_c, ema_w, ncnt, nw, ncb);
    } else {
        float* cnorm = (float*)d_ws;
        float* loss_arr = cnorm + K_CODES;
        hipMemsetAsync(loss_arr, 0, 256 * sizeof(float), stream);
        knorm<<<K_CODES / 4, 256, 0, stream>>>(cb, cnorm);
        kargmin_fp32<<<N_ROWS / 64, 256, 0, stream>>>(x, cb, cnorm, idxf);
        kquant<<<32768, 256, 0, stream>>>(x, cb, idxf, qout, nw, ncnt, loss_arr);
        kstats<<<1, 256, 0, stream>>>(ncnt, loss_arr, out);
        kfinal<<<K_CODES, C_DIM, 0, stream>>>(ema_c, ema_w, ncnt, nw, ncb);
    }
}

// Round 6
// 1123.644 us; speedup vs baseline: 3.4618x; 1.5874x over previous
//
#include <hip/hip_runtime.h>
#include <hip/hip_bf16.h>
#include <stdint.h>

#define N_ROWS 32768
#define K_CODES 8192
#define C_DIM 256
#define DECAYF 0.95f
#define COMMITF 0.25f
#define EPSF 1e-5f
#define RESC_EPS 0.02f
#define RESC_CAP 4096

// d_out layout (floats), reference return order
#define OFF_QUANT 0
#define OFF_ELOSS 8388608
#define OFF_PERP  8388609
#define OFF_UNIQ  8388610
#define OFF_NCB   8388611
#define OFF_NCNT  10485763
#define OFF_NW    10493955
#define OFF_IDX   12591107

typedef __hip_bfloat16 bf16;
typedef float f32x4 __attribute__((ext_vector_type(4)));
typedef short bf16x8 __attribute__((ext_vector_type(8)));
typedef unsigned long long u64;

#define SWZ(r) ((((r) >> 2) & 7) << 2)

#if defined(__has_builtin)
#if __has_builtin(__builtin_amdgcn_global_load_lds)
#define HAVE_GLDS 1
#endif
#endif
#ifdef HAVE_GLDS
#define GLDS16(g, l) __builtin_amdgcn_global_load_lds( \
    (const __attribute__((address_space(1))) void*)(uintptr_t)(g), \
    (__attribute__((address_space(3))) void*)(uint32_t)(uintptr_t)(l), 16, 0, 0)
#else
#define GLDS16(g, l) do { *(float4*)(l) = *(const float4*)(g); } while (0)
#endif

__device__ __forceinline__ uint32_t fkey(float f) {
    uint32_t b = __float_as_uint(f);
    return b ^ ((uint32_t)((int32_t)b >> 31) | 0x80000000u);
}
__device__ __forceinline__ float funkey(uint32_t k) {
    uint32_t b = (k & 0x80000000u) ? (k ^ 0x80000000u) : ~k;
    return __uint_as_float(b);
}
__device__ __forceinline__ void split2(float v, unsigned short& h, unsigned short& m) {
    bf16 hb = __float2bfloat16(v);
    float fh = __bfloat162float(hb);
    bf16 mb = __float2bfloat16(v - fh);
    h = *(unsigned short*)&hb; m = *(unsigned short*)&mb;
}
__device__ __forceinline__ float bf2f(unsigned short u) {
    return __bfloat162float(*(bf16*)&u);
}

// ---------------- codebook row squared-norms ----------------
__global__ void knorm(const float* __restrict__ cb, float* __restrict__ cnorm) {
    const int wid  = threadIdx.x >> 6;
    const int lane = threadIdx.x & 63;
    const int row  = blockIdx.x * 4 + wid;
    const float4 v = *(const float4*)(cb + (size_t)row * C_DIM + lane * 4);
    float s = v.x * v.x + v.y * v.y + v.z * v.z + v.w * v.w;
    #pragma unroll
    for (int off = 32; off; off >>= 1) s += __shfl_down(s, off);
    if (lane == 0) cnorm[row] = s;
}

// ---------------- split codebook into 2 bf16 planes ----------------
__global__ void ksplit_cb(const float* __restrict__ cb, unsigned short* __restrict__ Bsp) {
    const size_t plane = (size_t)K_CODES * C_DIM;
    const size_t i4 = ((size_t)blockIdx.x * 256 + threadIdx.x) * 4;
    const float4 v = *(const float4*)(cb + i4);
    ushort4 h, m;
    split2(v.x, h.x, m.x); split2(v.y, h.y, m.y);
    split2(v.z, h.z, m.z); split2(v.w, h.w, m.w);
    *(ushort4*)(Bsp + i4) = h;
    *(ushort4*)(Bsp + plane + i4) = m;
}

// ---------------- transpose x to [n][c] and split into 2 bf16 planes ----------------
__global__ __launch_bounds__(256)
void ksplit_x(const float* __restrict__ x, unsigned short* __restrict__ Asp) {
    __shared__ float xt[64][65];
    const int t = threadIdx.x;
    const int bid = blockIdx.x;        // 8 b * 4 ct * 64 st = 2048
    const int st = bid & 63;
    const int ct = (bid >> 6) & 3;
    const int b  = bid >> 8;
    const float* xb = x + ((size_t)b * C_DIM + ct * 64) * 4096 + st * 64;
    {
        const int s_l = t & 63, c0 = t >> 6;
        #pragma unroll
        for (int cc = 0; cc < 16; ++cc) {
            int c_l = cc * 4 + c0;
            xt[c_l][s_l] = xb[(size_t)c_l * 4096 + s_l];
        }
    }
    __syncthreads();
    const size_t plane = (size_t)N_ROWS * C_DIM;
    const int c2 = (t & 31) * 2;
    const int s0 = t >> 5;
    #pragma unroll
    for (int ww = 0; ww < 8; ++ww) {
        int s_o = ww * 8 + s0;
        float v0 = xt[c2][s_o], v1 = xt[c2 + 1][s_o];
        unsigned short h0, m0_, h1, m1_;
        split2(v0, h0, m0_); split2(v1, h1, m1_);
        size_t off = ((size_t)(b * 4096 + st * 64 + s_o)) * C_DIM + ct * 64 + c2;
        *(ushort2*)(Asp + off)         = make_ushort2(h0, h1);
        *(ushort2*)(Asp + plane + off) = make_ushort2(m0_, m1_);
    }
}

// ---------------- MFMA distance GEMM + per-row top-2 argmin ----------------
__global__ __launch_bounds__(512, 2)
void kargmin_mfma(const unsigned short* __restrict__ Asp, const unsigned short* __restrict__ Bsp,
                  const float* __restrict__ cnorm, u64* __restrict__ wsmin) {
    __shared__ unsigned short As[2][256 * 64];
    __shared__ unsigned short Bs[2][256 * 64];

    const int t = threadIdx.x;
    const int lane = t & 63;
    const int wid = t >> 6;
    const int swz = (blockIdx.x & 7) * 512 + (blockIdx.x >> 3);
    const int mtile = swz & 127;
    const int ntile = swz >> 7;
    const int m0 = mtile * 256;
    const int n0 = ntile * 256;
    const int wr = wid >> 2;
    const int wc = wid & 3;
    const int wm = wr * 128;
    const int wn = wc * 64;
    const int lm = lane & 15;
    const int lh = lane >> 4;
    const int l7 = lane & 7;
    const int NKT = 12;

    f32x4 acc[8][4];
    #pragma unroll
    for (int i = 0; i < 8; ++i)
        #pragma unroll
        for (int j = 0; j < 4; ++j) acc[i][j] = (f32x4){0.f, 0.f, 0.f, 0.f};

    const int PA[3] = {0, 0, 1};
    const int PB[3] = {0, 1, 0};

    const int sgr = t >> 3;
    const int gslot = (t & 7) ^ (sgr & 7);

    auto stage = [&](int kt, int buf) {
        const int seg = kt >> 2;
        const int kk0 = (kt & 3) * 64;
        const unsigned short* Ab = Asp + ((size_t)PA[seg] * N_ROWS + m0) * C_DIM + kk0;
        const unsigned short* Bb = Bsp + ((size_t)PB[seg] * K_CODES + n0) * C_DIM + kk0;
        #pragma unroll
        for (int it = 0; it < 4; ++it) {
            const int chunk = it * 512 + t;
            const int r = it * 64 + sgr;
            GLDS16(Ab + (size_t)r * C_DIM + gslot * 8, &As[buf][chunk * 8]);
            GLDS16(Bb + (size_t)r * C_DIM + gslot * 8, &Bs[buf][chunk * 8]);
        }
    };

    stage(0, 0);
    __syncthreads();

    for (int kt = 0; kt < NKT; ++kt) {
        const int cur = kt & 1;
        if (kt + 1 < NKT) stage(kt + 1, cur ^ 1);
        #pragma unroll
        for (int kh = 0; kh < 2; ++kh) {
            const int sw = ((kh * 4 + lh) ^ l7) * 8;
            bf16x8 a[8], b[4];
            #pragma unroll
            for (int j = 0; j < 4; ++j)
                b[j] = *(const bf16x8*)&Bs[cur][(wn + j * 16 + lm) * 64 + sw];
            #pragma unroll
            for (int i = 0; i < 8; ++i)
                a[i] = *(const bf16x8*)&As[cur][(wm + i * 16 + lm) * 64 + sw];
            #pragma unroll
            for (int i = 0; i < 8; ++i)
                #pragma unroll
                for (int j = 0; j < 4; ++j)
                    acc[i][j] = __builtin_amdgcn_mfma_f32_16x16x32_bf16(a[i], b[j], acc[i][j], 0, 0, 0);
        }
        __syncthreads();
    }

    float cn[4];
    #pragma unroll
    for (int j = 0; j < 4; ++j) cn[j] = cnorm[n0 + wn + j * 16 + lm];

    u64* redbuf = (u64*)&As[0][0];
    #pragma unroll
    for (int i = 0; i < 8; ++i) {
        u64 p1[4], p2[4];
        #pragma unroll
        for (int r = 0; r < 4; ++r) {
            u64 b1 = ~0ull, b2 = ~0ull;
            #pragma unroll
            for (int j = 0; j < 4; ++j) {
                float dist = fmaf(-2.f, acc[i][j][r], cn[j]);
                u64 pk = ((u64)fkey(dist) << 32) | (unsigned)(n0 + wn + j * 16 + lm);
                if (pk < b1) { b2 = b1; b1 = pk; }
                else if (pk < b2) b2 = pk;
            }
            p1[r] = b1; p2[r] = b2;
        }
        #pragma unroll
        for (int off = 1; off < 16; off <<= 1) {
            #pragma unroll
            for (int r = 0; r < 4; ++r) {
                u64 o1 = __shfl_xor(p1[r], off);
                u64 o2 = __shfl_xor(p2[r], off);
                u64 lo = p1[r] < o1 ? p1[r] : o1;
                u64 hi = p1[r] < o1 ? o1 : p1[r];
                u64 mn2 = p2[r] < o2 ? p2[r] : o2;
                p1[r] = lo;
                p2[r] = hi < mn2 ? hi : mn2;
            }
        }
        if (lm == 0) {
            #pragma unroll
            for (int r = 0; r < 4; ++r) {
                const int rl = wm + i * 16 + lh * 4 + r;
                redbuf[rl * 8 + wc * 2 + 0] = p1[r];
                redbuf[rl * 8 + wc * 2 + 1] = p2[r];
            }
        }
    }
    __syncthreads();
    if (t < 256) {
        u64 m1 = ~0ull, m2 = ~0ull;
        #pragma unroll
        for (int w = 0; w < 4; ++w) {
            u64 a1 = redbuf[t * 8 + w * 2 + 0];
            u64 a2 = redbuf[t * 8 + w * 2 + 1];
            u64 lo = m1 < a1 ? m1 : a1;
            u64 hi = m1 < a1 ? a1 : m1;
            u64 mn2 = m2 < a2 ? m2 : a2;
            m1 = lo;
            m2 = hi < mn2 ? hi : mn2;
        }
        size_t o = ((size_t)(m0 + t) * 32 + ntile) * 2;
        wsmin[o] = m1; wsmin[o + 1] = m2;
    }
}

// ---------------- combine per-ntile mins; flag near-ties ----------------
__global__ void kcombine(const u64* __restrict__ wsmin, float* __restrict__ idxf,
                         unsigned* __restrict__ rcnt, unsigned* __restrict__ rrows) {
    const int row = blockIdx.x * 256 + threadIdx.x;
    const u64* p = wsmin + (size_t)row * 64;
    u64 m1 = ~0ull, m2 = ~0ull;
    for (int i = 0; i < 64; i += 2) {
        u64 a = p[i], b = p[i + 1];
        u64 lo = a < m1 ? a : m1;
        u64 hi = a < m1 ? m1 : a;
        u64 c = m2 < b ? m2 : b;
        m1 = lo;
        m2 = hi < c ? hi : c;
    }
    idxf[row] = (float)(unsigned)(m1 & 0xffffffffu);
    float d1 = funkey((uint32_t)(m1 >> 32));
    float d2 = funkey((uint32_t)(m2 >> 32));
    if (d2 - d1 < RESC_EPS) {
        unsigned slot = atomicAdd(rcnt, 1u);
        if (slot < RESC_CAP) rrows[slot] = (unsigned)row;
    }
}

// ---------------- exact fp32 re-score for near-tie rows ----------------
__global__ __launch_bounds__(256)
void krescue(const float* __restrict__ x, const float* __restrict__ cb,
             const float* __restrict__ cnorm, const unsigned* __restrict__ rcnt,
             const unsigned* __restrict__ rrows, float* __restrict__ idxf) {
    __shared__ float xs[256];
    __shared__ u64 red[4];
    unsigned cnt = *rcnt; if (cnt > RESC_CAP) cnt = RESC_CAP;
    for (unsigned li = blockIdx.x; li < cnt; li += gridDim.x) {
        const int row = (int)rrows[li];
        const int b = row >> 12, s = row & 4095;
        xs[threadIdx.x] = x[((size_t)b * C_DIM + threadIdx.x) * 4096 + s];
        __syncthreads();
        u64 best = ~0ull;
        for (int k0 = 0; k0 < K_CODES; k0 += 256) {
            const int k = k0 + threadIdx.x;
            const float* cr = cb + (size_t)k * C_DIM;
            float dot = 0.f;
            #pragma unroll 8
            for (int c = 0; c < C_DIM; ++c) dot = fmaf(xs[c], cr[c], dot);
            float dist = fmaf(-2.f, dot, cnorm[k]);
            u64 pk = ((u64)fkey(dist) << 32) | (unsigned)k;
            if (pk < best) best = pk;
        }
        #pragma unroll
        for (int off = 32; off; off >>= 1) {
            u64 o = __shfl_down(best, off);
            if (o < best) best = o;
        }
        if ((threadIdx.x & 63) == 0) red[threadIdx.x >> 6] = best;
        __syncthreads();
        if (threadIdx.x == 0) {
            u64 r0 = red[0];
            #pragma unroll
            for (int w = 1; w < 4; ++w) if (red[w] < r0) r0 = red[w];
            idxf[row] = (float)(unsigned)(r0 & 0xffffffffu);
        }
        __syncthreads();
    }
}

// ---------------- CSR build: histogram / scan / scatter ----------------
__global__ void khist(const float* __restrict__ idxf, float* __restrict__ counts) {
    const int n = blockIdx.x * 256 + threadIdx.x;
    atomicAdd(&counts[(int)idxf[n]], 1.0f);
}

__global__ void kscan(const float* __restrict__ counts, unsigned* __restrict__ off,
                      unsigned* __restrict__ cursor) {
    __shared__ unsigned part[256];
    const int t = threadIdx.x;
    unsigned local[32];
    unsigned s = 0;
    #pragma unroll
    for (int i = 0; i < 32; ++i) { local[i] = s; s += (unsigned)counts[t * 32 + i]; }
    part[t] = s;
    __syncthreads();
    if (t == 0) {
        unsigned run = 0;
        for (int i = 0; i < 256; ++i) { unsigned v = part[i]; part[i] = run; run += v; }
    }
    __syncthreads();
    const unsigned base = part[t];
    #pragma unroll
    for (int i = 0; i < 32; ++i) {
        unsigned o = base + local[i];
        off[t * 32 + i] = o;
        cursor[t * 32 + i] = o;
    }
}

__global__ void kscatter(const float* __restrict__ idxf, unsigned* __restrict__ cursor,
                         unsigned* __restrict__ rowlist) {
    const int n = blockIdx.x * 256 + threadIdx.x;
    const int k = (int)idxf[n];
    unsigned pos = atomicAdd(&cursor[k], 1u);
    rowlist[pos] = (unsigned)n;
}

// ---------------- dw = segment_sum(x) via CSR, from bf16 h+m planes ----------------
__global__ void kdw(const unsigned short* __restrict__ Asp, const float* __restrict__ counts,
                    const unsigned* __restrict__ off, const unsigned* __restrict__ rowlist,
                    float* __restrict__ dwout) {
    const int k = blockIdx.x;
    const int lane = threadIdx.x;   // 64
    const int cnt = (int)counts[k];
    const unsigned base = off[k];
    const size_t plane = (size_t)N_ROWS * C_DIM;
    float4 acc = make_float4(0.f, 0.f, 0.f, 0.f);
    for (int i = 0; i < cnt; ++i) {
        const unsigned row = rowlist[base + i];
        const ushort4 h = *(const ushort4*)(Asp + (size_t)row * C_DIM + lane * 4);
        const ushort4 m = *(const ushort4*)(Asp + plane + (size_t)row * C_DIM + lane * 4);
        acc.x += bf2f(h.x) + bf2f(m.x);
        acc.y += bf2f(h.y) + bf2f(m.y);
        acc.z += bf2f(h.z) + bf2f(m.z);
        acc.w += bf2f(h.w) + bf2f(m.w);
    }
    *(float4*)(dwout + (size_t)k * C_DIM + lane * 4) = acc;
}

// ---------------- quantize (gather-transpose) + e_loss, no atomics on dw ----------------
__global__ __launch_bounds__(256)
void kquant2(const float* __restrict__ x, const float* __restrict__ cb,
             const float* __restrict__ idxf, float* __restrict__ qout,
             float* __restrict__ loss_arr) {
    __shared__ int ki[64];
    __shared__ float cbt[64][257];   // stride 257: column reads conflict-free
    const int t = threadIdx.x;
    const int bid = blockIdx.x;      // 512 = 8 b * 64 chunks of 64 s
    const int chunk = bid & 63;
    const int b = bid >> 6;
    const int s0 = chunk * 64;
    if (t < 64) ki[t] = (int)idxf[b * 4096 + s0 + t];
    __syncthreads();
    {
        const int lane = t & 63;
        const int rr = t >> 6;
        #pragma unroll
        for (int p = 0; p < 16; ++p) {
            const int r = p * 4 + rr;
            const float4 v = *(const float4*)(cb + (size_t)ki[r] * C_DIM + lane * 4);
            cbt[r][lane * 4 + 0] = v.x;
            cbt[r][lane * 4 + 1] = v.y;
            cbt[r][lane * 4 + 2] = v.z;
            cbt[r][lane * 4 + 3] = v.w;
        }
    }
    __syncthreads();
    const int sg = t & 15;           // s quad: s = sg*4
    const int c0 = t >> 4;           // 0..15
    float lsum = 0.f;
    #pragma unroll
    for (int cc = 0; cc < 16; ++cc) {
        const int c = cc * 16 + c0;
        const size_t go = ((size_t)b * C_DIM + c) * 4096 + s0 + sg * 4;
        const float4 xv = *(const float4*)(x + go);
        float qx = cbt[sg * 4 + 0][c];
        float qy = cbt[sg * 4 + 1][c];
        float qz = cbt[sg * 4 + 2][c];
        float qw = cbt[sg * 4 + 3][c];
        float4 st;
        st.x = xv.x + (qx - xv.x);
        st.y = xv.y + (qy - xv.y);
        st.z = xv.z + (qz - xv.z);
        st.w = xv.w + (qw - xv.w);
        *(float4*)(qout + go) = st;
        float dx = qx - xv.x, dy = qy - xv.y, dz = qz - xv.z, dw_ = qw - xv.w;
        lsum += dx * dx + dy * dy + dz * dz + dw_ * dw_;
    }
    #pragma unroll
    for (int off = 32; off; off >>= 1) lsum += __shfl_down(lsum, off);
    __shared__ float ps[4];
    if ((t & 63) == 0) ps[t >> 6] = lsum;
    __syncthreads();
    if (t == 0) atomicAdd(&loss_arr[bid & 255], ps[0] + ps[1] + ps[2] + ps[3]);
}

// ---------------- perplexity / unique / e_loss ----------------
__global__ void kstats(const float* __restrict__ counts, const float* __restrict__ loss_arr,
                       float* __restrict__ out) {
    const int t = threadIdx.x;
    float nz = 0.f, s = 0.f;
    for (int k = t; k < K_CODES; k += 256) {
        float cnt = counts[k];
        if (cnt != 0.f) nz += 1.f;
        float p = cnt * (1.f / 32768.f);
        s += p * logf(p + 1e-10f);
    }
    float ls = loss_arr[t];
    #pragma unroll
    for (int off = 32; off; off >>= 1) {
        s  += __shfl_down(s, off);
        nz += __shfl_down(nz, off);
        ls += __shfl_down(ls, off);
    }
    __shared__ float ss[4], zz[4], ll[4];
    const int wid = t >> 6, lane = t & 63;
    if (lane == 0) { ss[wid] = s; zz[wid] = nz; ll[wid] = ls; }
    __syncthreads();
    if (t == 0) {
        float st = ss[0] + ss[1] + ss[2] + ss[3];
        float zt = zz[0] + zz[1] + zz[2] + zz[3];
        float lt = ll[0] + ll[1] + ll[2] + ll[3];
        out[OFF_ELOSS] = COMMITF * lt / 8388608.f;
        out[OFF_PERP]  = expf(-st);
        out[OFF_UNIQ]  = zt;
    }
}

// ---------------- EMA finalize (counts from ws; no aliasing tricks) ----------------
__global__ void kfinal2(const float* __restrict__ ema_c, const float* __restrict__ ema_w,
                        const float* __restrict__ counts, float* __restrict__ dw /* raw in, nw out */,
                        float* __restrict__ ncb, float* __restrict__ ncnt_out) {
    const int k = blockIdx.x;
    const int c = threadIdx.x;
    const float ncnt = (DECAYF * ema_c[k] + (1.f - DECAYF) * counts[k] + EPSF)
                       / (8.f + (float)K_CODES * EPSF) * 8.f;
    const size_t o = (size_t)k * C_DIM + c;
    const float nwv = DECAYF * ema_w[o] + (1.f - DECAYF) * dw[o];
    dw[o]  = nwv;
    ncb[o] = nwv / ncnt;
    if (c == 0) ncnt_out[k] = ncnt;
}

// ======= fallback fp32 path (kept intact; used only if ws too small) =======
__launch_bounds__(256, 1)
__global__ void kargmin_fp32(const float* __restrict__ x, const float* __restrict__ cb,
                             const float* __restrict__ cnorm, float* __restrict__ idxf) {
    __shared__ float xs[64][256];
    __shared__ float es[64][256];
    const int t  = threadIdx.x;
    const int n0 = blockIdx.x * 64;
    const int b  = n0 >> 12;
    const int s0 = n0 & 4095;
    {
        const int r  = t & 63;
        const int c0 = t >> 6;
        const float* xb = x + (size_t)b * C_DIM * 4096 + s0 + r;
        const int sw = SWZ(r);
        #pragma unroll 8
        for (int cc = 0; cc < 64; ++cc) {
            int c = cc * 4 + c0;
            xs[r][c ^ sw] = xb[(size_t)c * 4096];
        }
    }
    const int mg  = t >> 4;
    const int ng  = t & 15;
    const int m0  = mg * 4;
    const int nn0 = ng * 4;
    const int swm = SWZ(m0);
    const int swn = SWZ(nn0);
    float minv[4] = {1e30f, 1e30f, 1e30f, 1e30f};
    int   mini[4] = {0, 0, 0, 0};
    for (int k0 = 0; k0 < K_CODES; k0 += 64) {
        __syncthreads();
        {
            const int lane = t & 63;
            const int cw   = t >> 6;
            #pragma unroll
            for (int p = 0; p < 16; ++p) {
                int code = p * 4 + cw;
                float4 v = *(const float4*)(cb + (size_t)(k0 + code) * C_DIM + lane * 4);
                *(float4*)&es[code][(lane * 4) ^ SWZ(code)] = v;
            }
        }
        float cn[4];
        #pragma unroll
        for (int j = 0; j < 4; ++j) cn[j] = cnorm[k0 + nn0 + j];
        __syncthreads();
        float acc[4][4];
        #pragma unroll
        for (int i = 0; i < 4; ++i)
            #pragma unroll
            for (int j = 0; j < 4; ++j) acc[i][j] = 0.f;
        #pragma unroll 4
        for (int c = 0; c < C_DIM; c += 4) {
            float4 xa[4], eb[4];
            #pragma unroll
            for (int i = 0; i < 4; ++i) xa[i] = *(const float4*)&xs[m0 + i][c ^ swm];
            #pragma unroll
            for (int j = 0; j < 4; ++j) eb[j] = *(const float4*)&es[nn0 + j][c ^ swn];
            #pragma unroll
            for (int i = 0; i < 4; ++i)
                #pragma unroll
                for (int j = 0; j < 4; ++j)
                    acc[i][j] += xa[i].x * eb[j].x + xa[i].y * eb[j].y +
                                 xa[i].z * eb[j].z + xa[i].w * eb[j].w;
        }
        #pragma unroll
        for (int j = 0; j < 4; ++j) {
            const int kg = k0 + nn0 + j;
            #pragma unroll
            for (int i = 0; i < 4; ++i) {
                float dist = fmaf(-2.f, acc[i][j], cn[j]);
                if (dist < minv[i]) { minv[i] = dist; mini[i] = kg; }
            }
        }
    }
    #pragma unroll
    for (int off = 1; off < 16; off <<= 1) {
        #pragma unroll
        for (int i = 0; i < 4; ++i) {
            float ov = __shfl_xor(minv[i], off);
            int   oi = __shfl_xor(mini[i], off);
            if (ov < minv[i] || (ov == minv[i] && oi < mini[i])) { minv[i] = ov; mini[i] = oi; }
        }
    }
    if (ng == 0) {
        #pragma unroll
        for (int i = 0; i < 4; ++i) idxf[n0 + m0 + i] = (float)mini[i];
    }
}

__global__ void kquant_legacy(const float* __restrict__ x, const float* __restrict__ cb,
                              const float* __restrict__ idxf, float* __restrict__ qout,
                              float* __restrict__ dw, float* __restrict__ counts,
                              float* __restrict__ loss_arr) {
    const int t   = threadIdx.x;
    const int bid = blockIdx.x;
    const int sc  = bid & 15;
    const int c   = (bid >> 4) & 255;
    const int b   = bid >> 12;
    const int s   = sc * 256 + t;
    const int n   = b * 4096 + s;
    const int k   = (int)idxf[n];
    const size_t xoff = ((size_t)b * C_DIM + c) * 4096 + s;
    const float xv = x[xoff];
    const float q  = cb[(size_t)k * C_DIM + c];
    qout[xoff] = xv + (q - xv);
    atomicAdd(&dw[(size_t)k * C_DIM + c], xv);
    if (c == 0) atomicAdd(&counts[k], 1.0f);
    float d = q - xv;
    float p = d * d;
    #pragma unroll
    for (int off = 32; off; off >>= 1) p += __shfl_down(p, off);
    __shared__ float ps[4];
    if ((t & 63) == 0) ps[t >> 6] = p;
    __syncthreads();
    if (t == 0) atomicAdd(&loss_arr[bid & 255], ps[0] + ps[1] + ps[2] + ps[3]);
}

__global__ void kfinal_legacy(const float* __restrict__ ema_c, const float* __restrict__ ema_w,
                              float* __restrict__ counts, float* __restrict__ dw,
                              float* __restrict__ ncb) {
    const int k = blockIdx.x;
    const int c = threadIdx.x;
    const float cnt  = counts[k];
    const float ncnt = (DECAYF * ema_c[k] + (1.f - DECAYF) * cnt + EPSF)
                       / (8.f + (float)K_CODES * EPSF) * 8.f;
    const size_t o = (size_t)k * C_DIM + c;
    const float nw = DECAYF * ema_w[o] + (1.f - DECAYF) * dw[o];
    __syncthreads();
    dw[o]  = nw;
    ncb[o] = nw / ncnt;
    if (c == 0) counts[k] = ncnt;
}

extern "C" void kernel_launch(void* const* d_in, const int* in_sizes, int n_in,
                              void* d_out, int out_size, void* d_ws, size_t ws_size,
                              hipStream_t stream) {
    const float* x     = (const float*)d_in[0];
    const float* cb    = (const float*)d_in[1];
    const float* ema_c = (const float*)d_in[2];
    const float* ema_w = (const float*)d_in[3];
    float* out = (float*)d_out;

    float* qout = out + OFF_QUANT;
    float* ncb  = out + OFF_NCB;
    float* ncnt = out + OFF_NCNT;
    float* nw   = out + OFF_NW;
    float* idxf = out + OFF_IDX;

    const size_t planeA = (size_t)2 * N_ROWS * C_DIM;   // bf16 elems (h,m)
    const size_t planeB = (size_t)2 * K_CODES * C_DIM;
    const size_t tail_f = K_CODES + 256 + K_CODES;                 // cnorm, loss, counts
    const size_t tail_u = 1 + RESC_CAP + K_CODES + K_CODES + N_ROWS; // rcnt, rrows, off, cursor, rowlist
    const size_t need = (planeA + planeB) * 2 + (tail_f + tail_u) * 4 + 64;
    const bool use_mfma = ws_size >= need;

    if (use_mfma) {
        unsigned short* Asp = (unsigned short*)d_ws;
        unsigned short* Bsp = Asp + planeA;
        float* cnorm      = (float*)(Bsp + planeB);
        float* loss_arr   = cnorm + K_CODES;
        float* counts_raw = loss_arr + 256;
        unsigned* rcnt    = (unsigned*)(counts_raw + K_CODES);
        unsigned* rrows   = rcnt + 1;
        unsigned* off     = rrows + RESC_CAP;
        unsigned* cursor  = off + K_CODES;
        unsigned* rowlist = cursor + K_CODES;
        u64* wsmin = (u64*)(out + OFF_QUANT);   // 16 MB, consumed before kquant2 writes qout

        hipMemsetAsync(loss_arr, 0, 256 * sizeof(float), stream);
        hipMemsetAsync(counts_raw, 0, K_CODES * sizeof(float), stream);
        hipMemsetAsync(rcnt, 0, sizeof(unsigned), stream);

        knorm<<<K_CODES / 4, 256, 0, stream>>>(cb, cnorm);
        ksplit_cb<<<(K_CODES * C_DIM / 4) / 256, 256, 0, stream>>>(cb, Bsp);
        ksplit_x<<<2048, 256, 0, stream>>>(x, Asp);
        kargmin_mfma<<<4096, 512, 0, stream>>>(Asp, Bsp, cnorm, wsmin);
        kcombine<<<N_ROWS / 256, 256, 0, stream>>>(wsmin, idxf, rcnt, rrows);
        krescue<<<128, 256, 0, stream>>>(x, cb, cnorm, rcnt, rrows, idxf);
        khist<<<N_ROWS / 256, 256, 0, stream>>>(idxf, counts_raw);
        kscan<<<1, 256, 0, stream>>>(counts_raw, off, cursor);
        kscatter<<<N_ROWS / 256, 256, 0, stream>>>(idxf, cursor, rowlist);
        kdw<<<K_CODES, 64, 0, stream>>>(Asp, counts_raw, off, rowlist, nw);
        kquant2<<<512, 256, 0, stream>>>(x, cb, idxf, qout, loss_arr);
        kstats<<<1, 256, 0, stream>>>(counts_raw, loss_arr, out);
        kfinal2<<<K_CODES, C_DIM, 0, stream>>>(ema_c, ema_w, counts_raw, nw, ncb, ncnt);
    } else {
        float* cnorm = (float*)d_ws;
        float* loss_arr = cnorm + K_CODES;
        hipMemsetAsync(ncnt, 0, K_CODES * sizeof(float), stream);
        hipMemsetAsync(nw, 0, (size_t)K_CODES * C_DIM * sizeof(float), stream);
        hipMemsetAsync(loss_arr, 0, 256 * sizeof(float), stream);
        knorm<<<K_CODES / 4, 256, 0, stream>>>(cb, cnorm);
        kargmin_fp32<<<N_ROWS / 64, 256, 0, stream>>>(x, cb, cnorm, idxf);
        kquant_legacy<<<32768, 256, 0, stream>>>(x, cb, idxf, qout, nw, ncnt, loss_arr);
        kstats<<<1, 256, 0, stream>>>(ncnt, loss_arr, out);
        kfinal_legacy<<<K_CODES, C_DIM, 0, stream>>>(ema_c, ema_w, ncnt, nw, ncb);
    }
}

// Round 7
// 1122.180 us; speedup vs baseline: 3.4664x; 1.0013x over previous
//
#include <hip/hip_runtime.h>
#include <hip/hip_bf16.h>
#include <stdint.h>

#define N_ROWS 32768
#define K_CODES 8192
#define C_DIM 256
#define DECAYF 0.95f
#define COMMITF 0.25f
#define EPSF 1e-5f
#define RESC_EPS 0.02f
#define RESC_CAP 4096

// d_out layout (floats), reference return order
#define OFF_QUANT 0
#define OFF_ELOSS 8388608
#define OFF_PERP  8388609
#define OFF_UNIQ  8388610
#define OFF_NCB   8388611
#define OFF_NCNT  10485763
#define OFF_NW    10493955
#define OFF_IDX   12591107

typedef __hip_bfloat16 bf16;
typedef float f32x4 __attribute__((ext_vector_type(4)));
typedef short bf16x8 __attribute__((ext_vector_type(8)));
typedef unsigned long long u64;

#define SWZ(r) ((((r) >> 2) & 7) << 2)

#if defined(__has_builtin)
#if __has_builtin(__builtin_amdgcn_global_load_lds)
#define HAVE_GLDS 1
#endif
#endif
#ifdef HAVE_GLDS
#define GLDS16(g, l) __builtin_amdgcn_global_load_lds( \
    (const __attribute__((address_space(1))) void*)(uintptr_t)(g), \
    (__attribute__((address_space(3))) void*)(uint32_t)(uintptr_t)(l), 16, 0, 0)
#else
#define GLDS16(g, l) do { *(float4*)(l) = *(const float4*)(g); } while (0)
#endif

__device__ __forceinline__ uint32_t fkey(float f) {
    uint32_t b = __float_as_uint(f);
    return b ^ ((uint32_t)((int32_t)b >> 31) | 0x80000000u);
}
__device__ __forceinline__ float funkey(uint32_t k) {
    uint32_t b = (k & 0x80000000u) ? (k ^ 0x80000000u) : ~k;
    return __uint_as_float(b);
}
__device__ __forceinline__ void split2(float v, unsigned short& h, unsigned short& m) {
    bf16 hb = __float2bfloat16(v);
    float fh = __bfloat162float(hb);
    bf16 mb = __float2bfloat16(v - fh);
    h = *(unsigned short*)&hb; m = *(unsigned short*)&mb;
}
__device__ __forceinline__ float bf2f(unsigned short u) {
    return __bfloat162float(*(bf16*)&u);
}

// ---------------- codebook row squared-norms (fallback path only) ----------------
__global__ void knorm(const float* __restrict__ cb, float* __restrict__ cnorm) {
    const int wid  = threadIdx.x >> 6;
    const int lane = threadIdx.x & 63;
    const int row  = blockIdx.x * 4 + wid;
    const float4 v = *(const float4*)(cb + (size_t)row * C_DIM + lane * 4);
    float s = v.x * v.x + v.y * v.y + v.z * v.z + v.w * v.w;
    #pragma unroll
    for (int off = 32; off; off >>= 1) s += __shfl_down(s, off);
    if (lane == 0) cnorm[row] = s;
}

// ---------------- split codebook into 2 bf16 planes + row norms (fused) ----------------
__global__ void ksplit_cb(const float* __restrict__ cb, unsigned short* __restrict__ Bsp,
                          float* __restrict__ cnorm) {
    const size_t plane = (size_t)K_CODES * C_DIM;
    const size_t i4 = ((size_t)blockIdx.x * 256 + threadIdx.x) * 4;
    const float4 v = *(const float4*)(cb + i4);
    ushort4 h, m;
    split2(v.x, h.x, m.x); split2(v.y, h.y, m.y);
    split2(v.z, h.z, m.z); split2(v.w, h.w, m.w);
    *(ushort4*)(Bsp + i4) = h;
    *(ushort4*)(Bsp + plane + i4) = m;
    // 64 consecutive lanes cover one 256-elem row: wave-aligned reduce
    float s = v.x * v.x + v.y * v.y + v.z * v.z + v.w * v.w;
    #pragma unroll
    for (int off = 32; off; off >>= 1) s += __shfl_down(s, off);
    if ((threadIdx.x & 63) == 0) cnorm[i4 >> 8] = s;
}

// ---------------- transpose x to [n][c] and split into 2 bf16 planes ----------------
__global__ __launch_bounds__(256)
void ksplit_x(const float* __restrict__ x, unsigned short* __restrict__ Asp) {
    __shared__ float xt[64][65];
    const int t = threadIdx.x;
    const int bid = blockIdx.x;        // 8 b * 4 ct * 64 st = 2048
    const int st = bid & 63;
    const int ct = (bid >> 6) & 3;
    const int b  = bid >> 8;
    const float* xb = x + ((size_t)b * C_DIM + ct * 64) * 4096 + st * 64;
    {
        const int s_l = t & 63, c0 = t >> 6;
        #pragma unroll
        for (int cc = 0; cc < 16; ++cc) {
            int c_l = cc * 4 + c0;
            xt[c_l][s_l] = xb[(size_t)c_l * 4096 + s_l];
        }
    }
    __syncthreads();
    const size_t plane = (size_t)N_ROWS * C_DIM;
    const int c2 = (t & 31) * 2;
    const int s0 = t >> 5;
    #pragma unroll
    for (int ww = 0; ww < 8; ++ww) {
        int s_o = ww * 8 + s0;
        float v0 = xt[c2][s_o], v1 = xt[c2 + 1][s_o];
        unsigned short h0, m0_, h1, m1_;
        split2(v0, h0, m0_); split2(v1, h1, m1_);
        size_t off = ((size_t)(b * 4096 + st * 64 + s_o)) * C_DIM + ct * 64 + c2;
        *(ushort2*)(Asp + off)         = make_ushort2(h0, h1);
        *(ushort2*)(Asp + plane + off) = make_ushort2(m0_, m1_);
    }
}

// ---------------- MFMA distance GEMM + per-row top-2 argmin ----------------
// 256x256 tile, 512 thr = 8 waves (2Mx4N), per-wave 128x64 (8x4 frags).
// 4-phase schedule per K-step: {ds_read subtile | stage half-tiles} ->
// s_barrier -> setprio(1) 16-MFMA setprio(0) -> s_barrier. All cross-wave
// LDS hazards resolve at the tile-boundary __syncthreads (in-flight there ==
// exactly this tile's loads, so the drain is not conservative).
__global__ __launch_bounds__(512, 2)
void kargmin_mfma(const unsigned short* __restrict__ Asp, const unsigned short* __restrict__ Bsp,
                  const float* __restrict__ cnorm, u64* __restrict__ wsmin) {
    __shared__ unsigned short As[2][256 * 64];
    __shared__ unsigned short Bs[2][256 * 64];

    const int t = threadIdx.x;
    const int lane = t & 63;
    const int wid = t >> 6;
    const int swz = (blockIdx.x & 7) * 512 + (blockIdx.x >> 3);
    const int mtile = swz & 127;
    const int ntile = swz >> 7;
    const int m0 = mtile * 256;
    const int n0 = ntile * 256;
    const int wr = wid >> 2;
    const int wc = wid & 3;
    const int wm = wr * 128;
    const int wn = wc * 64;
    const int lm = lane & 15;
    const int lh = lane >> 4;
    const int l7 = lane & 7;
    const int NKT = 12;

    f32x4 acc[8][4];
    #pragma unroll
    for (int i = 0; i < 8; ++i)
        #pragma unroll
        for (int j = 0; j < 4; ++j) acc[i][j] = (f32x4){0.f, 0.f, 0.f, 0.f};

    const int PA[3] = {0, 0, 1};
    const int PB[3] = {0, 1, 0};

    const int sgr = t >> 3;
    const int gslot = (t & 7) ^ (sgr & 7);

    auto stageA = [&](int kt, int buf) {
        const int seg = kt >> 2;
        const int kk0 = (kt & 3) * 64;
        const unsigned short* Ab = Asp + ((size_t)PA[seg] * N_ROWS + m0) * C_DIM + kk0;
        #pragma unroll
        for (int it = 0; it < 4; ++it) {
            const int chunk = it * 512 + t;
            const int r = it * 64 + sgr;
            GLDS16(Ab + (size_t)r * C_DIM + gslot * 8, &As[buf][chunk * 8]);
        }
    };
    auto stageB = [&](int kt, int buf) {
        const int seg = kt >> 2;
        const int kk0 = (kt & 3) * 64;
        const unsigned short* Bb = Bsp + ((size_t)PB[seg] * K_CODES + n0) * C_DIM + kk0;
        #pragma unroll
        for (int it = 0; it < 4; ++it) {
            const int chunk = it * 512 + t;
            const int r = it * 64 + sgr;
            GLDS16(Bb + (size_t)r * C_DIM + gslot * 8, &Bs[buf][chunk * 8]);
        }
    };

    stageA(0, 0);
    stageB(0, 0);

    const int sw0 = (lh ^ l7) * 8;           // kh=0 swizzled slot
    const int sw1 = ((4 + lh) ^ l7) * 8;     // kh=1 swizzled slot

    bf16x8 a[4][2], b0[2][2], b1[2][2];

    for (int kt = 0; kt < NKT; ++kt) {
        const int cur = kt & 1;
        __syncthreads();   // tile boundary: drains exactly this tile's staged loads

        // ---- phase 0: read a(i0..3) + b(j0..1); stage A(kt+1)
        #pragma unroll
        for (int i = 0; i < 4; ++i) {
            a[i][0] = *(const bf16x8*)&As[cur][(wm + i * 16 + lm) * 64 + sw0];
            a[i][1] = *(const bf16x8*)&As[cur][(wm + i * 16 + lm) * 64 + sw1];
        }
        #pragma unroll
        for (int j = 0; j < 2; ++j) {
            b0[j][0] = *(const bf16x8*)&Bs[cur][(wn + j * 16 + lm) * 64 + sw0];
            b0[j][1] = *(const bf16x8*)&Bs[cur][(wn + j * 16 + lm) * 64 + sw1];
        }
        if (kt + 1 < NKT) stageA(kt + 1, cur ^ 1);
        __builtin_amdgcn_s_barrier();
        __builtin_amdgcn_s_setprio(1);
        #pragma unroll
        for (int i = 0; i < 4; ++i)
            #pragma unroll
            for (int j = 0; j < 2; ++j) {
                acc[i][j] = __builtin_amdgcn_mfma_f32_16x16x32_bf16(a[i][0], b0[j][0], acc[i][j], 0, 0, 0);
                acc[i][j] = __builtin_amdgcn_mfma_f32_16x16x32_bf16(a[i][1], b0[j][1], acc[i][j], 0, 0, 0);
            }
        __builtin_amdgcn_s_setprio(0);
        __builtin_amdgcn_s_barrier();

        // ---- phase 1: read b(j2..3); stage B(kt+1)
        #pragma unroll
        for (int j = 0; j < 2; ++j) {
            b1[j][0] = *(const bf16x8*)&Bs[cur][(wn + (j + 2) * 16 + lm) * 64 + sw0];
            b1[j][1] = *(const bf16x8*)&Bs[cur][(wn + (j + 2) * 16 + lm) * 64 + sw1];
        }
        if (kt + 1 < NKT) stageB(kt + 1, cur ^ 1);
        __builtin_amdgcn_s_barrier();
        __builtin_amdgcn_s_setprio(1);
        #pragma unroll
        for (int i = 0; i < 4; ++i)
            #pragma unroll
            for (int j = 0; j < 2; ++j) {
                acc[i][j + 2] = __builtin_amdgcn_mfma_f32_16x16x32_bf16(a[i][0], b1[j][0], acc[i][j + 2], 0, 0, 0);
                acc[i][j + 2] = __builtin_amdgcn_mfma_f32_16x16x32_bf16(a[i][1], b1[j][1], acc[i][j + 2], 0, 0, 0);
            }
        __builtin_amdgcn_s_setprio(0);
        __builtin_amdgcn_s_barrier();

        // ---- phase 2: read a(i4..7)
        #pragma unroll
        for (int i = 0; i < 4; ++i) {
            a[i][0] = *(const bf16x8*)&As[cur][(wm + 64 + i * 16 + lm) * 64 + sw0];
            a[i][1] = *(const bf16x8*)&As[cur][(wm + 64 + i * 16 + lm) * 64 + sw1];
        }
        __builtin_amdgcn_s_barrier();
        __builtin_amdgcn_s_setprio(1);
        #pragma unroll
        for (int i = 0; i < 4; ++i)
            #pragma unroll
            for (int j = 0; j < 2; ++j) {
                acc[i + 4][j + 2] = __builtin_amdgcn_mfma_f32_16x16x32_bf16(a[i][0], b1[j][0], acc[i + 4][j + 2], 0, 0, 0);
                acc[i + 4][j + 2] = __builtin_amdgcn_mfma_f32_16x16x32_bf16(a[i][1], b1[j][1], acc[i + 4][j + 2], 0, 0, 0);
            }
        __builtin_amdgcn_s_setprio(0);
        __builtin_amdgcn_s_barrier();

        // ---- phase 3: pure-reg MFMA; next tile's __syncthreads closes it
        __builtin_amdgcn_s_setprio(1);
        #pragma unroll
        for (int i = 0; i < 4; ++i)
            #pragma unroll
            for (int j = 0; j < 2; ++j) {
                acc[i + 4][j] = __builtin_amdgcn_mfma_f32_16x16x32_bf16(a[i][0], b0[j][0], acc[i + 4][j], 0, 0, 0);
                acc[i + 4][j] = __builtin_amdgcn_mfma_f32_16x16x32_bf16(a[i][1], b0[j][1], acc[i + 4][j], 0, 0, 0);
            }
        __builtin_amdgcn_s_setprio(0);
    }

    // epilogue: dist = cnorm - 2*dot ; per-row top-2 (distkey<<32 | code)
    float cn[4];
    #pragma unroll
    for (int j = 0; j < 4; ++j) cn[j] = cnorm[n0 + wn + j * 16 + lm];

    u64* redbuf = (u64*)&As[0][0];
    #pragma unroll
    for (int i = 0; i < 8; ++i) {
        u64 p1[4], p2[4];
        #pragma unroll
        for (int r = 0; r < 4; ++r) {
            u64 b1_ = ~0ull, b2_ = ~0ull;
            #pragma unroll
            for (int j = 0; j < 4; ++j) {
                float dist = fmaf(-2.f, acc[i][j][r], cn[j]);
                u64 pk = ((u64)fkey(dist) << 32) | (unsigned)(n0 + wn + j * 16 + lm);
                if (pk < b1_) { b2_ = b1_; b1_ = pk; }
                else if (pk < b2_) b2_ = pk;
            }
            p1[r] = b1_; p2[r] = b2_;
        }
        #pragma unroll
        for (int off = 1; off < 16; off <<= 1) {
            #pragma unroll
            for (int r = 0; r < 4; ++r) {
                u64 o1 = __shfl_xor(p1[r], off);
                u64 o2 = __shfl_xor(p2[r], off);
                u64 lo = p1[r] < o1 ? p1[r] : o1;
                u64 hi = p1[r] < o1 ? o1 : p1[r];
                u64 mn2 = p2[r] < o2 ? p2[r] : o2;
                p1[r] = lo;
                p2[r] = hi < mn2 ? hi : mn2;
            }
        }
        if (lm == 0) {
            #pragma unroll
            for (int r = 0; r < 4; ++r) {
                const int rl = wm + i * 16 + lh * 4 + r;
                redbuf[rl * 8 + wc * 2 + 0] = p1[r];
                redbuf[rl * 8 + wc * 2 + 1] = p2[r];
            }
        }
    }
    __syncthreads();
    if (t < 256) {
        u64 m1 = ~0ull, m2 = ~0ull;
        #pragma unroll
        for (int w = 0; w < 4; ++w) {
            u64 a1 = redbuf[t * 8 + w * 2 + 0];
            u64 a2 = redbuf[t * 8 + w * 2 + 1];
            u64 lo = m1 < a1 ? m1 : a1;
            u64 hi = m1 < a1 ? a1 : m1;
            u64 mn2 = m2 < a2 ? m2 : a2;
            m1 = lo;
            m2 = hi < mn2 ? hi : mn2;
        }
        size_t o = ((size_t)(m0 + t) * 32 + ntile) * 2;
        wsmin[o] = m1; wsmin[o + 1] = m2;
    }
}

// ---------------- combine per-ntile mins; histogram; flag near-ties ----------------
__global__ void kcombine(const u64* __restrict__ wsmin, float* __restrict__ idxf,
                         unsigned* __restrict__ rcnt, unsigned* __restrict__ rrows,
                         float* __restrict__ counts) {
    const int row = blockIdx.x * 256 + threadIdx.x;
    const u64* p = wsmin + (size_t)row * 64;
    u64 m1 = ~0ull, m2 = ~0ull;
    for (int i = 0; i < 64; i += 2) {
        u64 a = p[i], b = p[i + 1];
        u64 lo = a < m1 ? a : m1;
        u64 hi = a < m1 ? m1 : a;
        u64 c = m2 < b ? m2 : b;
        m1 = lo;
        m2 = hi < c ? hi : c;
    }
    const int k = (int)(unsigned)(m1 & 0xffffffffu);
    idxf[row] = (float)k;
    atomicAdd(&counts[k], 1.0f);
    float d1 = funkey((uint32_t)(m1 >> 32));
    float d2 = funkey((uint32_t)(m2 >> 32));
    if (d2 - d1 < RESC_EPS) {
        unsigned slot = atomicAdd(rcnt, 1u);
        if (slot < RESC_CAP) rrows[slot] = (unsigned)row;
    }
}

// ---------------- exact fp32 re-score for near-tie rows (fixes counts on flip) ----------------
__global__ __launch_bounds__(256)
void krescue(const float* __restrict__ x, const float* __restrict__ cb,
             const float* __restrict__ cnorm, const unsigned* __restrict__ rcnt,
             const unsigned* __restrict__ rrows, float* __restrict__ idxf,
             float* __restrict__ counts) {
    __shared__ float xs[256];
    __shared__ u64 red[4];
    unsigned cnt = *rcnt; if (cnt > RESC_CAP) cnt = RESC_CAP;
    for (unsigned li = blockIdx.x; li < cnt; li += gridDim.x) {
        const int row = (int)rrows[li];
        const int b = row >> 12, s = row & 4095;
        xs[threadIdx.x] = x[((size_t)b * C_DIM + threadIdx.x) * 4096 + s];
        __syncthreads();
        u64 best = ~0ull;
        for (int k0 = 0; k0 < K_CODES; k0 += 256) {
            const int k = k0 + threadIdx.x;
            const float* cr = cb + (size_t)k * C_DIM;
            float dot = 0.f;
            #pragma unroll 8
            for (int c = 0; c < C_DIM; ++c) dot = fmaf(xs[c], cr[c], dot);
            float dist = fmaf(-2.f, dot, cnorm[k]);
            u64 pk = ((u64)fkey(dist) << 32) | (unsigned)k;
            if (pk < best) best = pk;
        }
        #pragma unroll
        for (int off = 32; off; off >>= 1) {
            u64 o = __shfl_down(best, off);
            if (o < best) best = o;
        }
        if ((threadIdx.x & 63) == 0) red[threadIdx.x >> 6] = best;
        __syncthreads();
        if (threadIdx.x == 0) {
            u64 r0 = red[0];
            #pragma unroll
            for (int w = 1; w < 4; ++w) if (red[w] < r0) r0 = red[w];
            const int knew = (int)(unsigned)(r0 & 0xffffffffu);
            const int kold = (int)idxf[row];
            if (knew != kold) {
                atomicAdd(&counts[kold], -1.0f);
                atomicAdd(&counts[knew], 1.0f);
                idxf[row] = (float)knew;
            }
        }
        __syncthreads();
    }
}

// ---------------- CSR build: scan / scatter ----------------
__global__ void kscan(const float* __restrict__ counts, unsigned* __restrict__ off,
                      unsigned* __restrict__ cursor) {
    __shared__ unsigned part[256];
    const int t = threadIdx.x;
    unsigned local[32];
    unsigned s = 0;
    #pragma unroll
    for (int i = 0; i < 32; ++i) { local[i] = s; s += (unsigned)counts[t * 32 + i]; }
    part[t] = s;
    __syncthreads();
    if (t == 0) {
        unsigned run = 0;
        for (int i = 0; i < 256; ++i) { unsigned v = part[i]; part[i] = run; run += v; }
    }
    __syncthreads();
    const unsigned base = part[t];
    #pragma unroll
    for (int i = 0; i < 32; ++i) {
        unsigned o = base + local[i];
        off[t * 32 + i] = o;
        cursor[t * 32 + i] = o;
    }
}

__global__ void kscatter(const float* __restrict__ idxf, unsigned* __restrict__ cursor,
                         unsigned* __restrict__ rowlist) {
    const int n = blockIdx.x * 256 + threadIdx.x;
    const int k = (int)idxf[n];
    unsigned pos = atomicAdd(&cursor[k], 1u);
    rowlist[pos] = (unsigned)n;
}

// ---------------- dw = segment_sum(x) via CSR, from bf16 h+m planes ----------------
__global__ void kdw(const unsigned short* __restrict__ Asp, const float* __restrict__ counts,
                    const unsigned* __restrict__ off, const unsigned* __restrict__ rowlist,
                    float* __restrict__ dwout) {
    const int k = blockIdx.x;
    const int lane = threadIdx.x;   // 64
    const int cnt = (int)counts[k];
    const unsigned base = off[k];
    const size_t plane = (size_t)N_ROWS * C_DIM;
    float4 acc = make_float4(0.f, 0.f, 0.f, 0.f);
    for (int i = 0; i < cnt; ++i) {
        const unsigned row = rowlist[base + i];
        const ushort4 h = *(const ushort4*)(Asp + (size_t)row * C_DIM + lane * 4);
        const ushort4 m = *(const ushort4*)(Asp + plane + (size_t)row * C_DIM + lane * 4);
        acc.x += bf2f(h.x) + bf2f(m.x);
        acc.y += bf2f(h.y) + bf2f(m.y);
        acc.z += bf2f(h.z) + bf2f(m.z);
        acc.w += bf2f(h.w) + bf2f(m.w);
    }
    *(float4*)(dwout + (size_t)k * C_DIM + lane * 4) = acc;
}

// ---------------- quantize (gather-transpose) + e_loss ----------------
__global__ __launch_bounds__(256)
void kquant2(const float* __restrict__ x, const float* __restrict__ cb,
             const float* __restrict__ idxf, float* __restrict__ qout,
             float* __restrict__ loss_arr) {
    __shared__ int ki[64];
    __shared__ float cbt[64][257];
    const int t = threadIdx.x;
    const int bid = blockIdx.x;
    const int chunk = bid & 63;
    const int b = bid >> 6;
    const int s0 = chunk * 64;
    if (t < 64) ki[t] = (int)idxf[b * 4096 + s0 + t];
    __syncthreads();
    {
        const int lane = t & 63;
        const int rr = t >> 6;
        #pragma unroll
        for (int p = 0; p < 16; ++p) {
            const int r = p * 4 + rr;
            const float4 v = *(const float4*)(cb + (size_t)ki[r] * C_DIM + lane * 4);
            cbt[r][lane * 4 + 0] = v.x;
            cbt[r][lane * 4 + 1] = v.y;
            cbt[r][lane * 4 + 2] = v.z;
            cbt[r][lane * 4 + 3] = v.w;
        }
    }
    __syncthreads();
    const int sg = t & 15;
    const int c0 = t >> 4;
    float lsum = 0.f;
    #pragma unroll
    for (int cc = 0; cc < 16; ++cc) {
        const int c = cc * 16 + c0;
        const size_t go = ((size_t)b * C_DIM + c) * 4096 + s0 + sg * 4;
        const float4 xv = *(const float4*)(x + go);
        float qx = cbt[sg * 4 + 0][c];
        float qy = cbt[sg * 4 + 1][c];
        float qz = cbt[sg * 4 + 2][c];
        float qw = cbt[sg * 4 + 3][c];
        float4 st;
        st.x = xv.x + (qx - xv.x);
        st.y = xv.y + (qy - xv.y);
        st.z = xv.z + (qz - xv.z);
        st.w = xv.w + (qw - xv.w);
        *(float4*)(qout + go) = st;
        float dx = qx - xv.x, dy = qy - xv.y, dz = qz - xv.z, dw_ = qw - xv.w;
        lsum += dx * dx + dy * dy + dz * dz + dw_ * dw_;
    }
    #pragma unroll
    for (int off = 32; off; off >>= 1) lsum += __shfl_down(lsum, off);
    __shared__ float ps[4];
    if ((t & 63) == 0) ps[t >> 6] = lsum;
    __syncthreads();
    if (t == 0) atomicAdd(&loss_arr[bid & 255], ps[0] + ps[1] + ps[2] + ps[3]);
}

// ---------------- perplexity / unique / e_loss ----------------
__global__ void kstats(const float* __restrict__ counts, const float* __restrict__ loss_arr,
                       float* __restrict__ out) {
    const int t = threadIdx.x;
    float nz = 0.f, s = 0.f;
    for (int k = t; k < K_CODES; k += 256) {
        float cnt = counts[k];
        if (cnt != 0.f) nz += 1.f;
        float p = cnt * (1.f / 32768.f);
        s += p * logf(p + 1e-10f);
    }
    float ls = loss_arr[t];
    #pragma unroll
    for (int off = 32; off; off >>= 1) {
        s  += __shfl_down(s, off);
        nz += __shfl_down(nz, off);
        ls += __shfl_down(ls, off);
    }
    __shared__ float ss[4], zz[4], ll[4];
    const int wid = t >> 6, lane = t & 63;
    if (lane == 0) { ss[wid] = s; zz[wid] = nz; ll[wid] = ls; }
    __syncthreads();
    if (t == 0) {
        float st = ss[0] + ss[1] + ss[2] + ss[3];
        float zt = zz[0] + zz[1] + zz[2] + zz[3];
        float lt = ll[0] + ll[1] + ll[2] + ll[3];
        out[OFF_ELOSS] = COMMITF * lt / 8388608.f;
        out[OFF_PERP]  = expf(-st);
        out[OFF_UNIQ]  = zt;
    }
}

// ---------------- EMA finalize ----------------
__global__ void kfinal2(const float* __restrict__ ema_c, const float* __restrict__ ema_w,
                        const float* __restrict__ counts, float* __restrict__ dw,
                        float* __restrict__ ncb, float* __restrict__ ncnt_out) {
    const int k = blockIdx.x;
    const int c = threadIdx.x;
    const float ncnt = (DECAYF * ema_c[k] + (1.f - DECAYF) * counts[k] + EPSF)
                       / (8.f + (float)K_CODES * EPSF) * 8.f;
    const size_t o = (size_t)k * C_DIM + c;
    const float nwv = DECAYF * ema_w[o] + (1.f - DECAYF) * dw[o];
    dw[o]  = nwv;
    ncb[o] = nwv / ncnt;
    if (c == 0) ncnt_out[k] = ncnt;
}

// ======= fallback fp32 path (used only if ws too small) =======
__launch_bounds__(256, 1)
__global__ void kargmin_fp32(const float* __restrict__ x, const float* __restrict__ cb,
                             const float* __restrict__ cnorm, float* __restrict__ idxf) {
    __shared__ float xs[64][256];
    __shared__ float es[64][256];
    const int t  = threadIdx.x;
    const int n0 = blockIdx.x * 64;
    const int b  = n0 >> 12;
    const int s0 = n0 & 4095;
    {
        const int r  = t & 63;
        const int c0 = t >> 6;
        const float* xb = x + (size_t)b * C_DIM * 4096 + s0 + r;
        const int sw = SWZ(r);
        #pragma unroll 8
        for (int cc = 0; cc < 64; ++cc) {
            int c = cc * 4 + c0;
            xs[r][c ^ sw] = xb[(size_t)c * 4096];
        }
    }
    const int mg  = t >> 4;
    const int ng  = t & 15;
    const int m0  = mg * 4;
    const int nn0 = ng * 4;
    const int swm = SWZ(m0);
    const int swn = SWZ(nn0);
    float minv[4] = {1e30f, 1e30f, 1e30f, 1e30f};
    int   mini[4] = {0, 0, 0, 0};
    for (int k0 = 0; k0 < K_CODES; k0 += 64) {
        __syncthreads();
        {
            const int lane = t & 63;
            const int cw   = t >> 6;
            #pragma unroll
            for (int p = 0; p < 16; ++p) {
                int code = p * 4 + cw;
                float4 v = *(const float4*)(cb + (size_t)(k0 + code) * C_DIM + lane * 4);
                *(float4*)&es[code][(lane * 4) ^ SWZ(code)] = v;
            }
        }
        float cn[4];
        #pragma unroll
        for (int j = 0; j < 4; ++j) cn[j] = cnorm[k0 + nn0 + j];
        __syncthreads();
        float acc[4][4];
        #pragma unroll
        for (int i = 0; i < 4; ++i)
            #pragma unroll
            for (int j = 0; j < 4; ++j) acc[i][j] = 0.f;
        #pragma unroll 4
        for (int c = 0; c < C_DIM; c += 4) {
            float4 xa[4], eb[4];
            #pragma unroll
            for (int i = 0; i < 4; ++i) xa[i] = *(const float4*)&xs[m0 + i][c ^ swm];
            #pragma unroll
            for (int j = 0; j < 4; ++j) eb[j] = *(const float4*)&es[nn0 + j][c ^ swn];
            #pragma unroll
            for (int i = 0; i < 4; ++i)
                #pragma unroll
                for (int j = 0; j < 4; ++j)
                    acc[i][j] += xa[i].x * eb[j].x + xa[i].y * eb[j].y +
                                 xa[i].z * eb[j].z + xa[i].w * eb[j].w;
        }
        #pragma unroll
        for (int j = 0; j < 4; ++j) {
            const int kg = k0 + nn0 + j;
            #pragma unroll
            for (int i = 0; i < 4; ++i) {
                float dist = fmaf(-2.f, acc[i][j], cn[j]);
                if (dist < minv[i]) { minv[i] = dist; mini[i] = kg; }
            }
        }
    }
    #pragma unroll
    for (int off = 1; off < 16; off <<= 1) {
        #pragma unroll
        for (int i = 0; i < 4; ++i) {
            float ov = __shfl_xor(minv[i], off);
            int   oi = __shfl_xor(mini[i], off);
            if (ov < minv[i] || (ov == minv[i] && oi < mini[i])) { minv[i] = ov; mini[i] = oi; }
        }
    }
    if (ng == 0) {
        #pragma unroll
        for (int i = 0; i < 4; ++i) idxf[n0 + m0 + i] = (float)mini[i];
    }
}

__global__ void kquant_legacy(const float* __restrict__ x, const float* __restrict__ cb,
                              const float* __restrict__ idxf, float* __restrict__ qout,
                              float* __restrict__ dw, float* __restrict__ counts,
                              float* __restrict__ loss_arr) {
    const int t   = threadIdx.x;
    const int bid = blockIdx.x;
    const int sc  = bid & 15;
    const int c   = (bid >> 4) & 255;
    const int b   = bid >> 12;
    const int s   = sc * 256 + t;
    const int n   = b * 4096 + s;
    const int k   = (int)idxf[n];
    const size_t xoff = ((size_t)b * C_DIM + c) * 4096 + s;
    const float xv = x[xoff];
    const float q  = cb[(size_t)k * C_DIM + c];
    qout[xoff] = xv + (q - xv);
    atomicAdd(&dw[(size_t)k * C_DIM + c], xv);
    if (c == 0) atomicAdd(&counts[k], 1.0f);
    float d = q - xv;
    float p = d * d;
    #pragma unroll
    for (int off = 32; off; off >>= 1) p += __shfl_down(p, off);
    __shared__ float ps[4];
    if ((t & 63) == 0) ps[t >> 6] = p;
    __syncthreads();
    if (t == 0) atomicAdd(&loss_arr[bid & 255], ps[0] + ps[1] + ps[2] + ps[3]);
}

__global__ void kfinal_legacy(const float* __restrict__ ema_c, const float* __restrict__ ema_w,
                              float* __restrict__ counts, float* __restrict__ dw,
                              float* __restrict__ ncb) {
    const int k = blockIdx.x;
    const int c = threadIdx.x;
    const float cnt  = counts[k];
    const float ncnt = (DECAYF * ema_c[k] + (1.f - DECAYF) * cnt + EPSF)
                       / (8.f + (float)K_CODES * EPSF) * 8.f;
    const size_t o = (size_t)k * C_DIM + c;
    const float nw = DECAYF * ema_w[o] + (1.f - DECAYF) * dw[o];
    __syncthreads();
    dw[o]  = nw;
    ncb[o] = nw / ncnt;
    if (c == 0) counts[k] = ncnt;
}

extern "C" void kernel_launch(void* const* d_in, const int* in_sizes, int n_in,
                              void* d_out, int out_size, void* d_ws, size_t ws_size,
                              hipStream_t stream) {
    const float* x     = (const float*)d_in[0];
    const float* cb    = (const float*)d_in[1];
    const float* ema_c = (const float*)d_in[2];
    const float* ema_w = (const float*)d_in[3];
    float* out = (float*)d_out;

    float* qout = out + OFF_QUANT;
    float* ncb  = out + OFF_NCB;
    float* ncnt = out + OFF_NCNT;
    float* nw   = out + OFF_NW;
    float* idxf = out + OFF_IDX;

    const size_t planeA = (size_t)2 * N_ROWS * C_DIM;   // bf16 elems (h,m)
    const size_t planeB = (size_t)2 * K_CODES * C_DIM;
    const size_t tail_f = K_CODES + 256 + K_CODES;
    const size_t tail_u = 1 + RESC_CAP + K_CODES + K_CODES + N_ROWS;
    const size_t need = (planeA + planeB) * 2 + (tail_f + tail_u) * 4 + 64;
    const bool use_mfma = ws_size >= need;

    if (use_mfma) {
        unsigned short* Asp = (unsigned short*)d_ws;
        unsigned short* Bsp = Asp + planeA;
        float* cnorm      = (float*)(Bsp + planeB);
        float* loss_arr   = cnorm + K_CODES;
        float* counts_raw = loss_arr + 256;
        unsigned* rcnt    = (unsigned*)(counts_raw + K_CODES);
        unsigned* rrows   = rcnt + 1;
        unsigned* off     = rrows + RESC_CAP;
        unsigned* cursor  = off + K_CODES;
        unsigned* rowlist = cursor + K_CODES;
        u64* wsmin = (u64*)(out + OFF_QUANT);   // 16 MB, consumed before kquant2 writes qout

        hipMemsetAsync(loss_arr, 0, 256 * sizeof(float), stream);
        hipMemsetAsync(counts_raw, 0, K_CODES * sizeof(float), stream);
        hipMemsetAsync(rcnt, 0, sizeof(unsigned), stream);

        ksplit_cb<<<(K_CODES * C_DIM / 4) / 256, 256, 0, stream>>>(cb, Bsp, cnorm);
        ksplit_x<<<2048, 256, 0, stream>>>(x, Asp);
        kargmin_mfma<<<4096, 512, 0, stream>>>(Asp, Bsp, cnorm, wsmin);
        kcombine<<<N_ROWS / 256, 256, 0, stream>>>(wsmin, idxf, rcnt, rrows, counts_raw);
        krescue<<<256, 256, 0, stream>>>(x, cb, cnorm, rcnt, rrows, idxf, counts_raw);
        kscan<<<1, 256, 0, stream>>>(counts_raw, off, cursor);
        kscatter<<<N_ROWS / 256, 256, 0, stream>>>(idxf, cursor, rowlist);
        kdw<<<K_CODES, 64, 0, stream>>>(Asp, counts_raw, off, rowlist, nw);
        kquant2<<<512, 256, 0, stream>>>(x, cb, idxf, qout, loss_arr);
        kstats<<<1, 256, 0, stream>>>(counts_raw, loss_arr, out);
        kfinal2<<<K_CODES, C_DIM, 0, stream>>>(ema_c, ema_w, counts_raw, nw, ncb, ncnt);
    } else {
        float* cnorm = (float*)d_ws;
        float* loss_arr = cnorm + K_CODES;
        hipMemsetAsync(ncnt, 0, K_CODES * sizeof(float), stream);
        hipMemsetAsync(nw, 0, (size_t)K_CODES * C_DIM * sizeof(float), stream);
        hipMemsetAsync(loss_arr, 0, 256 * sizeof(float), stream);
        knorm<<<K_CODES / 4, 256, 0, stream>>>(cb, cnorm);
        kargmin_fp32<<<N_ROWS / 64, 256, 0, stream>>>(x, cb, cnorm, idxf);
        kquant_legacy<<<32768, 256, 0, stream>>>(x, cb, idxf, qout, nw, ncnt, loss_arr);
        kstats<<<1, 256, 0, stream>>>(ncnt, loss_arr, out);
        kfinal_legacy<<<K_CODES, C_DIM, 0, stream>>>(ema_c, ema_w, ncnt, nw, ncb);
    }
}